// Round 15
// baseline (486.771 us; speedup 1.0000x reference)
//
#include <hip/hip_runtime.h>

// Round 15: single change vs round 14 — CB capped at 2048 so the per-chunk
// intermediate working set (~105MB) is Infinity-Cache(L3)-resident; all
// producer->consumer activation traffic becomes L3 hits instead of HBM
// round-trips. Pipeline runs twice (b0g chunk loop, already verified).

typedef unsigned short u16;
typedef __attribute__((ext_vector_type(8))) short bf16x8;
typedef __attribute__((ext_vector_type(4))) float f32x4;
typedef __attribute__((ext_vector_type(8))) unsigned short u16x8;
typedef __attribute__((ext_vector_type(2))) unsigned int u32x2;

__device__ __forceinline__ float bf2f(u16 u) {
  return __uint_as_float(((unsigned)u) << 16);
}
__device__ __forceinline__ u16 f2bf(float f) {
  unsigned u = __float_as_uint(f);
  return (u16)((u + 0x7FFFu + ((u >> 16) & 1u)) >> 16);   // RNE
}

#define Z4 make_float4(0.f, 0.f, 0.f, 0.f)

// ---- fp32 ws region offsets (floats) ----
#define OF_CS01   0        // 81
#define OF_CS1    81       // 30
#define OF_CSR    111      // 30
#define OF_CSAC   141      // 125
#define OF_CS02   266      // 10
#define OF_CSCC2  276      // 1
#define OF_L01T   280      // 127*84  [i][a pad 84]
#define OF_R01T   10948    // 127*84
#define OF_SWT    21616    // 81*64   [a][j2 pad 64]
#define OF_CB1T   26800    // 15*25   [k=c5*3+dh][c]
#define OF_C1T    27175    // 50*75   [k=c*2+dc][m]
#define OF_SCT    30928    // 30*20
#define OF_CA2T   31528    // 250*28  [k][c pad 28]
#define OF_WT2    38528    // u16[128][256] bf16 weights for k6 MFMA
#define OF_ZPAD   54912    // 8 floats of zeros (pad source for global_load_lds)
#define F32_TOTAL 54920

// ---- activation pool (u16 rows, pitch CB), lifetimes overlapped ----
#define R_XT   0      // 635
#define R_XL   635    // 405
#define R_YA   1040   // 405
#define R_ZA   1445   // 2025
#define R_P    3470   // 1500
#define R_Q    4970   // 300   (..5270)
#define R_V4A  5270   // 6000  (1500 ushort4-rows) [K4..K5]
#define R_V1   11270  // 1500  [K4..K5]
#define R_VRP  12770  // 3750  planar v right: [h=0..4][c*30+j] [K4..K6]
#define R_TP   16520  // 9000  planar t: [h=0..3][m*30+j]       [K5..K6]
#define R_X2   0      // 11250 [K6..K7]  rows = (h3*30+j)*125+o
#define R_XJ   12770  // 3750  [K7..K8a]
#define ROWS_TOTAL 25520

struct Ctx {
  const float *x, *ca1_w, *ca1_b, *l01_b, *r01_b, *cb1_b, *cc1_w, *cc1_b;
  const float *c1_b, *l1_b, *c2_b, *ca_b, *ra_b, *ca2_b, *l02_b;
  const float *cb2_w, *cb2_b, *cc2_w, *cc2_b, *r02_b, *fl_w, *fl_b;
  const float *l01_w, *r01_w, *l1_w, *ra_w, *c1_w, *c2_w, *ca_w, *cb1_w;
  const float *l02_w, *r02_w, *ca2_w;
  float *F;
  float *zAcc;      // [CB]
  float *yAcc;      // [3][CB]
  u16 *A;
  float *out;
  int CB;
  int b0g;
};

// ---------- K0C: constants + transposed/padded weights. grid(32) ----------
__global__ __launch_bounds__(256) void k0c(Ctx C) {
  const int t0 = blockIdx.x * 256 + threadIdx.x;
  const int NT = 32 * 256;
  float* F = C.F;
  for (int k = t0; k < 277; k += NT) {
    float s = 0.f;
    if (k < 81)       { for (int i = 0; i < 127; ++i) s += C.l01_w[k * 127 + i]; F[OF_CS01 + k] = s; }
    else if (k < 111) { int j = k - 81;  for (int a = 0; a < 81; ++a) s += C.l1_w[j * 81 + a]; F[OF_CS1 + j] = s; }
    else if (k < 141) { int j = k - 111; for (int a = 0; a < 81; ++a) s += C.ra_w[j * 81 + a]; F[OF_CSR + j] = s; }
    else if (k < 266) { int o = k - 141; for (int i = 0; i < 75; ++i) s += C.ca_w[o * 75 + i]; F[OF_CSAC + o] = s; }
    else if (k < 276) { int q = k - 266; for (int j = 0; j < 30; ++j) s += C.l02_w[q * 30 + j]; F[OF_CS02 + q] = s; }
    else              { float ss = 0.f; for (int o = 0; o < 125; ++o) ss += C.cc2_w[o]; F[OF_CSCC2] = ss; }
  }
  for (int e = t0; e < 8; e += NT) F[OF_ZPAD + e] = 0.f;
  for (int e = t0; e < 10668; e += NT) { int i = e / 84, a = e % 84;
    F[OF_L01T + e] = (a < 81) ? C.l01_w[a * 127 + i] : 0.f; }
  for (int e = t0; e < 10668; e += NT) { int i = e / 84, a = e % 84;
    F[OF_R01T + e] = (a < 81) ? C.r01_w[a * 127 + i] : 0.f; }
  for (int e = t0; e < 5184; e += NT)  { int a = e / 64, j2 = e % 64;
    F[OF_SWT + e] = (j2 < 30) ? C.l1_w[j2 * 81 + a]
                  : (j2 < 60) ? C.ra_w[(j2 - 30) * 81 + a] : 0.f; }
  for (int e = t0; e < 375; e += NT)   { int k = e / 25, c = e % 25; F[OF_CB1T + e] = C.cb1_w[c * 15 + k]; }
  for (int e = t0; e < 3750; e += NT)  { int k = e / 75, m = e % 75; F[OF_C1T + e] = C.c1_w[m * 50 + k]; }
  for (int e = t0; e < 600; e += NT)   { int j = e / 20, q2 = e % 20;
    F[OF_SCT + e] = (q2 < 10) ? C.l02_w[q2 * 30 + j] : C.r02_w[(q2 - 10) * 30 + j]; }
  for (int e = t0; e < 7000; e += NT)  { int k = e / 28, c = e % 28;
    F[OF_CA2T + e] = (c < 25) ? C.ca2_w[c * 250 + k] : 0.f; }
  u16* WT2 = (u16*)(F + OF_WT2);
  for (int e = t0; e < 32768; e += NT) {
    int o = e >> 8, k = e & 255;
    float v = 0.f;
    if (o < 125) {
      if (k < 150) v = C.c2_w[o * 150 + k];
      else if (k >= 160 && k < 235) v = C.ca_w[o * 75 + (k - 160)];
    }
    WT2[e] = f2bf(v);
  }
}

// ---------- K0T: transpose x -> xT[635][CB] bf16. grid (CB/64, 10) ----------
__global__ __launch_bounds__(256) void k0t(Ctx C) {
  __shared__ float tile[64][65];
  const int tid = threadIdx.x;
  const int b0 = blockIdx.x * 64;
  const int i0 = blockIdx.y * 64;
  for (int e = tid; e < 64 * 64; e += 256) {
    int s = e >> 6, ii = e & 63, gi = i0 + ii;
    if (gi < 635) tile[s][ii] = C.x[(size_t)(C.b0g + b0 + s) * 635 + gi];
  }
  __syncthreads();
  const int lane = tid & 63, wv = tid >> 6;
  u16* xT = C.A + (size_t)R_XT * C.CB;
#pragma unroll
  for (int k = 0; k < 16; ++k) {
    int r = wv * 16 + k, gi = i0 + r;
    if (gi < 635) xT[(size_t)gi * C.CB + b0 + lane] = f2bf(tile[lane][r]);
  }
}

// ---------- K1: XL = l01*x, yA = r01*x + r01_b. grid (CB/256, 30) ----------
__global__ __launch_bounds__(256) void k1(Ctx C) {
  const int col = blockIdx.x * 256 + threadIdx.x;
  if (col >= C.CB) return;
  const int g = blockIdx.y, type = g / 15, r = g % 15, h = r / 3, a0 = (r % 3) * 28;
  const size_t cb = (size_t)C.CB;
  const u16* __restrict__ xT = C.A + (size_t)R_XT * cb;
  const float* __restrict__ wT = C.F + (type ? OF_R01T : OF_L01T) + a0;
  float4 A0=Z4,A1=Z4,A2=Z4,A3=Z4,A4=Z4,A5=Z4,A6=Z4;
  for (int i = 0; i < 127; ++i) {
    float xv = bf2f(xT[(size_t)(h * 127 + i) * cb + col]);
    const float4* __restrict__ W = (const float4*)(wT + i * 84);
#define K1F(Aq, P) { float4 w = W[P]; Aq.x += w.x*xv; Aq.y += w.y*xv; Aq.z += w.z*xv; Aq.w += w.w*xv; }
    K1F(A0,0) K1F(A1,1) K1F(A2,2) K1F(A3,3) K1F(A4,4) K1F(A5,5) K1F(A6,6)
#undef K1F
  }
  u16* dst = C.A + (size_t)(type ? R_YA : R_XL) * cb;
  auto wr = [&](int a, float v) {
    if (a < 81) {
      float rr = v + (type ? C.r01_b[a] : 0.f);
      dst[(size_t)(h * 81 + a) * cb + col] = f2bf(rr);
    }
  };
#define K1O(Aq, P) { wr(a0+4*P+0, Aq.x); wr(a0+4*P+1, Aq.y); wr(a0+4*P+2, Aq.z); wr(a0+4*P+3, Aq.w); }
  K1O(A0,0) K1O(A1,1) K1O(A2,2) K1O(A3,3) K1O(A4,4) K1O(A5,5) K1O(A6,6)
#undef K1O
}

// ---------- K2: zA = relu(conv_ca1(XL) + ca1_b*S01 + l01_b). grid (CB/256, 75) ----------
__global__ __launch_bounds__(256) void k2(Ctx C) {
  const int col = blockIdx.x * 256 + threadIdx.x;
  if (col >= C.CB) return;
  const int g = blockIdx.y, c5 = g / 15, r = g % 15, h = r / 3, a0 = (r % 3) * 27;
  const u16* __restrict__ XL = C.A + (size_t)R_XL * C.CB;
  const float* __restrict__ F = C.F;
  float acc[27];
  float cb = C.ca1_b[c5];
#pragma unroll
  for (int a = 0; a < 27; ++a) acc[a] = cb * F[OF_CS01 + a0 + a] + C.l01_b[a0 + a];
#pragma unroll
  for (int dh = 0; dh < 3; ++dh) {
    int hp = h - 1 + dh;
    if (hp < 0 || hp > 4) continue;
    float w = C.ca1_w[c5 * 3 + dh];
#pragma unroll
    for (int a = 0; a < 27; ++a) acc[a] += w * bf2f(XL[(size_t)(hp * 81 + a0 + a) * C.CB + col]);
  }
  u16* zA = C.A + (size_t)R_ZA * C.CB;
#pragma unroll
  for (int a = 0; a < 27; ++a)
    zA[(size_t)((c5 * 5 + h) * 81 + a0 + a) * C.CB + col] = f2bf(fmaxf(acc[a], 0.f));
}

// ---------- K3: P = SW*zA, Q = SW*yA. grid (CB/256, 60) ----------
__global__ __launch_bounds__(256) void k3(Ctx C) {
  const int col = blockIdx.x * 256 + threadIdx.x;
  if (col >= C.CB) return;
  const int g = blockIdx.y, pair = g >> 1, j0 = (g & 1) * 32;
  const bool isP = (pair < 25);
  const size_t cb = (size_t)C.CB;
  const u16* __restrict__ src = C.A + (size_t)(isP ? (R_ZA + pair * 81) : (R_YA + (pair - 25) * 81)) * cb;
  const float* __restrict__ SWT = C.F + OF_SWT + j0;
  float4 A0=Z4,A1=Z4,A2=Z4,A3=Z4,A4=Z4,A5=Z4,A6=Z4,A7=Z4;
  for (int a = 0; a < 81; ++a) {
    float xv = bf2f(src[(size_t)a * cb + col]);
    const float4* __restrict__ W = (const float4*)(SWT + a * 64);
#define K3F(Aq, P) { float4 w = W[P]; Aq.x += w.x*xv; Aq.y += w.y*xv; Aq.z += w.z*xv; Aq.w += w.w*xv; }
    K3F(A0,0) K3F(A1,1) K3F(A2,2) K3F(A3,3) K3F(A4,4) K3F(A5,5) K3F(A6,6) K3F(A7,7)
#undef K3F
  }
  u16* dst = C.A + (size_t)(isP ? (R_P + pair * 60) : (R_Q + (pair - 25) * 60)) * cb;
  auto wr = [&](int j2, float v) {
    if (j2 < 60) dst[(size_t)j2 * cb + col] = f2bf(v);
  };
#define K3O(Aq, P) { wr(j0+4*P+0, Aq.x); wr(j0+4*P+1, Aq.y); wr(j0+4*P+2, Aq.z); wr(j0+4*P+3, Aq.w); }
  K3O(A0,0) K3O(A1,1) K3O(A2,2) K3O(A3,3) K3O(A4,4) K3O(A5,5) K3O(A6,6) K3O(A7,7)
#undef K3O
}

// ---------- K4: v packed + planar right-half. grid (CB/256, 300) ----------
__global__ __launch_bounds__(256) void k4(Ctx C) {
  const int col = blockIdx.x * 256 + threadIdx.x;
  if (col >= C.CB) return;
  const int g = blockIdx.y, cg = g / 60, j2 = g % 60;
  const size_t cb = (size_t)C.CB;
  const u16* __restrict__ Pb = C.A + (size_t)R_P * cb;
  const u16* __restrict__ Qb = C.A + (size_t)R_Q * cb;
  const float* __restrict__ F = C.F;
  float sj = (j2 < 30) ? F[OF_CS1 + j2] : F[OF_CSR + (j2 - 30)];
  float acc[5][5];
#pragma unroll
  for (int cl = 0; cl < 5; ++cl) {
    int c = cg * 5 + cl;
    float base = (C.cb1_b[c] + C.cc1_b[c]) * sj;
    float cw = C.cc1_w[c];
#pragma unroll
    for (int h = 0; h < 5; ++h)
      acc[cl][h] = base + cw * bf2f(Qb[(size_t)(h * 60 + j2) * cb + col]);
  }
#pragma unroll
  for (int c5 = 0; c5 < 5; ++c5)
#pragma unroll
    for (int hp = 0; hp < 5; ++hp) {
      float pv = bf2f(Pb[(size_t)((c5 * 5 + hp) * 60 + j2) * cb + col]);
#pragma unroll
      for (int dh = 0; dh < 3; ++dh) {
        int h = hp + 1 - dh;
        if (h < 0 || h > 4) continue;
        const float* __restrict__ w = F + OF_CB1T + (c5 * 3 + dh) * 25 + cg * 5;
#pragma unroll
        for (int cl = 0; cl < 5; ++cl) acc[cl][h] += w[cl] * pv;
      }
    }
  u16* v4 = C.A + (size_t)R_V4A * cb;
  u16* v1 = C.A + (size_t)R_V1 * cb;
#pragma unroll
  for (int cl = 0; cl < 5; ++cl) {
    int row = (cg * 5 + cl) * 60 + j2;
    ushort4 pk;
    pk.x = f2bf(acc[cl][0]); pk.y = f2bf(acc[cl][1]);
    pk.z = f2bf(acc[cl][2]); pk.w = f2bf(acc[cl][3]);
    *(ushort4*)(v4 + ((size_t)row * cb + col) * 4) = pk;
    v1[(size_t)row * cb + col] = f2bf(acc[cl][4]);
  }
  if (j2 >= 30) {
    u16* vrp = C.A + (size_t)R_VRP * cb;
    int jr = j2 - 30;
#pragma unroll
    for (int cl = 0; cl < 5; ++cl) {
      int base = (cg * 5 + cl) * 30 + jr;
      vrp[(size_t)(base)        * cb + col] = f2bf(acc[cl][0]);
      vrp[(size_t)(base + 750)  * cb + col] = f2bf(acc[cl][1]);
      vrp[(size_t)(base + 1500) * cb + col] = f2bf(acc[cl][2]);
      vrp[(size_t)(base + 2250) * cb + col] = f2bf(acc[cl][3]);
      vrp[(size_t)(base + 3000) * cb + col] = f2bf(acc[cl][4]);
    }
  }
}

// ---------- K5: t planar. 15 named float4 (components = h). grid (CB/256, 150) ----------
__global__ __launch_bounds__(256, 2) void k5(Ctx C) {
  const int col = blockIdx.x * 256 + threadIdx.x;
  if (col >= C.CB) return;
  const int g = blockIdx.y, mg = g / 30, j = g % 30;
  const size_t cb = (size_t)C.CB;
  const u16* __restrict__ v4 = C.A + (size_t)R_V4A * cb;
  const u16* __restrict__ v1 = C.A + (size_t)R_V1 * cb;
  const float* __restrict__ F = C.F;
  float s1 = F[OF_CS1 + j], lb = C.l1_b[j];
  float4 B0,B1,B2,B3,B4,B5,B6,B7,B8,B9,B10,B11,B12,B13,B14;
#define K5I(Bq, P) { float bb = C.c1_b[mg*15+P] * s1 + lb; Bq = make_float4(bb,bb,bb,bb); }
  K5I(B0,0) K5I(B1,1) K5I(B2,2) K5I(B3,3) K5I(B4,4) K5I(B5,5) K5I(B6,6) K5I(B7,7)
  K5I(B8,8) K5I(B9,9) K5I(B10,10) K5I(B11,11) K5I(B12,12) K5I(B13,13) K5I(B14,14)
#undef K5I
  for (int c = 0; c < 25; ++c) {
    int row = c * 60 + j;
    ushort4 pk = *(const ushort4*)(v4 + ((size_t)row * cb + col) * 4);
    float x0 = bf2f(pk.x), x1 = bf2f(pk.y), x2 = bf2f(pk.z), x3 = bf2f(pk.w);
    float x4 = bf2f(v1[(size_t)row * cb + col]);
    const float* __restrict__ wp0 = F + OF_C1T + (c * 2) * 75 + mg * 15;
    const float* __restrict__ wp1 = wp0 + 75;
#define K5F(Bq, P) { float w0v = wp0[P], w1v = wp1[P]; \
    Bq.x += w0v*x0 + w1v*x1; Bq.y += w0v*x1 + w1v*x2; \
    Bq.z += w0v*x2 + w1v*x3; Bq.w += w0v*x3 + w1v*x4; }
    K5F(B0,0) K5F(B1,1) K5F(B2,2) K5F(B3,3) K5F(B4,4) K5F(B5,5) K5F(B6,6) K5F(B7,7)
    K5F(B8,8) K5F(B9,9) K5F(B10,10) K5F(B11,11) K5F(B12,12) K5F(B13,13) K5F(B14,14)
#undef K5F
  }
  u16* tp = C.A + (size_t)R_TP * cb;
#define K5O(Bq, P) { int rb = (mg*15+P)*30 + j; \
    tp[(size_t)(rb)        * cb + col] = f2bf(fmaxf(Bq.x, 0.f)); \
    tp[(size_t)(rb + 2250) * cb + col] = f2bf(fmaxf(Bq.y, 0.f)); \
    tp[(size_t)(rb + 4500) * cb + col] = f2bf(fmaxf(Bq.z, 0.f)); \
    tp[(size_t)(rb + 6750) * cb + col] = f2bf(fmaxf(Bq.w, 0.f)); }
  K5O(B0,0) K5O(B1,1) K5O(B2,2) K5O(B3,3) K5O(B4,4) K5O(B5,5) K5O(B6,6) K5O(B7,7)
  K5O(B8,8) K5O(B9,9) K5O(B10,10) K5O(B11,11) K5O(B12,12) K5O(B13,13) K5O(B14,14)
#undef K5O
}

// ---------- K6M: x2 via MFMA; wave = 2 o-tiles x 8 M-tiles, B in regs. grid (CB/128, 90) ----------
// LDS: byte(k,m) = (k>>2)*1024 + (m>>4)*128 + (k&3)*32 + (m&15)*2  (64KB).
// tr-read register addr = (2q)*1024 + lc*8 (bit7 clear); mg/kb/s strides via
// offset immediates. (round-14 verified)
union CvtAF { u32x2 p[2]; bf16x8 v; };

#define RD(D, TA, OFF) asm volatile("ds_read_b64_tr_b16 %0, %1 offset:" OFF : "=&v"(D) : "v"(TA));
#define TRS_EVEN(TA) \
  RD(p00,TA,"0")     RD(p01,TA,"1024")  RD(p10,TA,"8192")  RD(p11,TA,"9216") \
  RD(p20,TA,"16384") RD(p21,TA,"17408") RD(p30,TA,"24576") RD(p31,TA,"25600") \
  RD(p40,TA,"32768") RD(p41,TA,"33792") RD(p50,TA,"40960") RD(p51,TA,"41984") \
  RD(p60,TA,"49152") RD(p61,TA,"50176") RD(p70,TA,"57344") RD(p71,TA,"58368")
#define TRS_ODD(TA) \
  RD(p00,TA,"128")   RD(p01,TA,"1152")  RD(p10,TA,"8320")  RD(p11,TA,"9344") \
  RD(p20,TA,"16512") RD(p21,TA,"17536") RD(p30,TA,"24704") RD(p31,TA,"25728") \
  RD(p40,TA,"32896") RD(p41,TA,"33920") RD(p50,TA,"41088") RD(p51,TA,"42112") \
  RD(p60,TA,"49280") RD(p61,TA,"50304") RD(p70,TA,"57472") RD(p71,TA,"58496")

__global__ __launch_bounds__(256, 2) void k6m(Ctx C) {
  __shared__ u16 sA[32768];   // 64 KB
  const int tid = threadIdx.x;
  const int col0 = blockIdx.x * 128;
  const int gy = blockIdx.y;
  const int j = gy / 3, h3 = gy % 3;
  const size_t cb = (size_t)C.CB;
  const u16* __restrict__ A_ = C.A;
  const u16* __restrict__ WT2 = (const u16*)(C.F + OF_WT2);
  const float* __restrict__ F = C.F;

  // ---- stage A-tile via global_load_lds (r11-verified) ----
  const int x = tid & 63, wv = tid >> 6;
  const int klane = (x >> 1) & 3;
  const int m0s = ((x >> 3) << 4) + ((x & 1) << 3);
  const u16* zsrc = (const u16*)(F + OF_ZPAD);
#pragma unroll
  for (int p = 0; p < 16; ++p) {
    int k = p * 16 + wv * 4 + klane;
    const u16* src;
    bool pad = (k >= 150 && k < 160) || (k >= 235);
    if (pad) {
      src = zsrc;
    } else {
      int srow;
      if (k < 150) srow = R_TP + (h3 + (k & 1)) * 2250 + (k >> 1) * 30 + j;
      else { int kk = k - 160; int c = kk / 3; srow = R_VRP + (h3 + (kk - c * 3)) * 750 + c * 30 + j; }
      src = A_ + (size_t)srow * cb + col0 + m0s;
    }
    __builtin_amdgcn_global_load_lds(
        (const __attribute__((address_space(1))) void*)src,
        (__attribute__((address_space(3))) void*)&sA[(p * 4 + wv) * 512],
        16, 0, 0);
  }

  // ---- B-fragments into registers (16, loaded once; overlaps staging) ----
  const int l = tid & 63, w = tid >> 6;
  const int lc = l & 15, q = l >> 4;
  const u16* wbA = WT2 + (size_t)(w * 32 + lc) * 256 + q * 8;        // o-tile 2w
  const u16* wbB = WT2 + (size_t)(w * 32 + 16 + lc) * 256 + q * 8;   // o-tile 2w+1
  bf16x8 b00 = *(const bf16x8*)(wbA + 0*32), b01 = *(const bf16x8*)(wbA + 1*32),
         b02 = *(const bf16x8*)(wbA + 2*32), b03 = *(const bf16x8*)(wbA + 3*32),
         b04 = *(const bf16x8*)(wbA + 4*32), b05 = *(const bf16x8*)(wbA + 5*32),
         b06 = *(const bf16x8*)(wbA + 6*32), b07 = *(const bf16x8*)(wbA + 7*32);
  bf16x8 b10 = *(const bf16x8*)(wbB + 0*32), b11 = *(const bf16x8*)(wbB + 1*32),
         b12 = *(const bf16x8*)(wbB + 2*32), b13 = *(const bf16x8*)(wbB + 3*32),
         b14 = *(const bf16x8*)(wbB + 4*32), b15 = *(const bf16x8*)(wbB + 5*32),
         b16 = *(const bf16x8*)(wbB + 6*32), b17 = *(const bf16x8*)(wbB + 7*32);

  // ---- per-lane epilogue constants ----
  float rbj = C.ra_b[j];
  u16* x2b = C.A + (size_t)R_X2 * cb;
  const size_t rowbase = (size_t)(h3 * 30 + j) * 125;
  const int o0 = w * 32 + lc;              // < 125 always (<=111)
  const int o1 = o0 + 16;                  // up to 127; guard at store
  const int o1c = (o1 < 125) ? o1 : 0;
  float bs0 = C.c2_b[o0] + C.ca_b[o0] + rbj * F[OF_CSAC + o0];
  float bs1 = C.c2_b[o1c] + C.ca_b[o1c] + rbj * F[OF_CSAC + o1c];

  __syncthreads();

  unsigned ldsbase = (unsigned)(size_t)(&sA[0]);
  const unsigned ta0 = ldsbase + (unsigned)((2 * q) * 1024 + lc * 8);
  const unsigned ta1 = ta0 + 256;
  const unsigned ta2 = ta0 + 512;
  const unsigned ta3 = ta0 + 768;

  u32x2 p00,p01, p10,p11, p20,p21, p30,p31, p40,p41, p50,p51, p60,p61, p70,p71;

  TRS_EVEN(ta0)   // prologue: mg=0 fragments in flight

#define MM(FS, BA, BB) \
    a0 = __builtin_amdgcn_mfma_f32_16x16x32_bf16(FS, BA, a0, 0, 0, 0); \
    a1 = __builtin_amdgcn_mfma_f32_16x16x32_bf16(FS, BB, a1, 0, 0, 0);

#define MG_BODY(MG, ...) { \
    asm volatile("s_waitcnt lgkmcnt(0)" ::: "memory"); \
    __builtin_amdgcn_sched_barrier(0); \
    bf16x8 f0,f1,f2,f3,f4,f5,f6,f7; \
    { CvtAF c_; c_.p[0]=p00; c_.p[1]=p01; f0=c_.v; } \
    { CvtAF c_; c_.p[0]=p10; c_.p[1]=p11; f1=c_.v; } \
    { CvtAF c_; c_.p[0]=p20; c_.p[1]=p21; f2=c_.v; } \
    { CvtAF c_; c_.p[0]=p30; c_.p[1]=p31; f3=c_.v; } \
    { CvtAF c_; c_.p[0]=p40; c_.p[1]=p41; f4=c_.v; } \
    { CvtAF c_; c_.p[0]=p50; c_.p[1]=p51; f5=c_.v; } \
    { CvtAF c_; c_.p[0]=p60; c_.p[1]=p61; f6=c_.v; } \
    { CvtAF c_; c_.p[0]=p70; c_.p[1]=p71; f7=c_.v; } \
    __VA_ARGS__ \
    f32x4 a0 = {0.f,0.f,0.f,0.f}, a1 = {0.f,0.f,0.f,0.f}; \
    MM(f0,b00,b10) MM(f1,b01,b11) MM(f2,b02,b12) MM(f3,b03,b13) \
    MM(f4,b04,b14) MM(f5,b05,b15) MM(f6,b06,b16) MM(f7,b07,b17) \
    const int cw = col0 + (MG) * 16 + q * 4; \
    { ushort4 pk; pk.x = f2bf(a0[0]+bs0); pk.y = f2bf(a0[1]+bs0); \
      pk.z = f2bf(a0[2]+bs0); pk.w = f2bf(a0[3]+bs0); \
      *(ushort4*)(x2b + (rowbase + o0) * cb + cw) = pk; } \
    if (o1 < 125) { ushort4 pk; pk.x = f2bf(a1[0]+bs1); pk.y = f2bf(a1[1]+bs1); \
      pk.z = f2bf(a1[2]+bs1); pk.w = f2bf(a1[3]+bs1); \
      *(ushort4*)(x2b + (rowbase + o1) * cb + cw) = pk; } \
  }

  MG_BODY(0, TRS_ODD(ta0))
  MG_BODY(1, TRS_EVEN(ta1))
  MG_BODY(2, TRS_ODD(ta1))
  MG_BODY(3, TRS_EVEN(ta2))
  MG_BODY(4, TRS_ODD(ta2))
  MG_BODY(5, TRS_EVEN(ta3))
  MG_BODY(6, TRS_ODD(ta3))
  MG_BODY(7)
#undef MG_BODY
#undef MM
}

// ---------- K7: XJ_left + fold right into yAcc. grid (CB/256, 375) ----------
__global__ __launch_bounds__(256) void k7(Ctx C) {
  const int col = blockIdx.x * 256 + threadIdx.x;
  if (col >= C.CB) return;
  const int g = blockIdx.y;               // g = o*3 + h3
  const int o = g / 3, h3 = g % 3;
  const size_t cb = (size_t)C.CB;
  const u16* __restrict__ x2b = C.A + (size_t)R_X2 * cb;
  const float* __restrict__ SCT = C.F + OF_SCT;
  float4 A0=Z4,A1=Z4,A2=Z4,A3=Z4,A4=Z4;
  for (int j = 0; j < 30; ++j) {
    float xv = bf2f(x2b[(size_t)((h3 * 30 + j) * 125 + o) * cb + col]);
    const float4* __restrict__ W = (const float4*)(SCT + j * 20);
#define K7F(Aq, P) { float4 w = W[P]; Aq.x += w.x*xv; Aq.y += w.y*xv; Aq.z += w.z*xv; Aq.w += w.w*xv; }
    K7F(A0,0) K7F(A1,1) K7F(A2,2) K7F(A3,3) K7F(A4,4)
#undef K7F
  }
  u16* XJ = C.A + (size_t)R_XJ * cb;
  auto wq = [&](int qq, float v) { XJ[(size_t)(g * 10 + qq) * cb + col] = f2bf(v); };
  wq(0,A0.x); wq(1,A0.y); wq(2,A0.z); wq(3,A0.w);
  wq(4,A1.x); wq(5,A1.y); wq(6,A1.z); wq(7,A1.w);
  wq(8,A2.x); wq(9,A2.y);
  float s = C.fl_w[0]*A2.z + C.fl_w[1]*A2.w
          + C.fl_w[2]*A3.x + C.fl_w[3]*A3.y + C.fl_w[4]*A3.z + C.fl_w[5]*A3.w
          + C.fl_w[6]*A4.x + C.fl_w[7]*A4.y + C.fl_w[8]*A4.z + C.fl_w[9]*A4.w;
  atomicAdd(&C.yAcc[(size_t)h3 * C.CB + col], C.cc2_w[o] * s);
}

// ---------- K8a: zC in regs; fold cb2+fl into zAcc. grid (CB/256, 20) ----------
__global__ __launch_bounds__(256) void k8a(Ctx C) {
  const int col = blockIdx.x * 256 + threadIdx.x;
  if (col >= C.CB) return;
  const int g = blockIdx.y, hh = g / 10, q = g % 10;
  const size_t cb = (size_t)C.CB;
  const u16* __restrict__ XJ = C.A + (size_t)R_XJ * cb;
  const float* __restrict__ F = C.F;
  float4 A0=Z4,A1=Z4,A2=Z4,A3=Z4,A4=Z4,A5=Z4,A6=Z4;
  for (int k = 0; k < 250; ++k) {
    int o = k >> 1, dh = k & 1;
    float xv = bf2f(XJ[(size_t)((o * 3 + hh + dh) * 10 + q) * cb + col]);
    const float4* __restrict__ W = (const float4*)(F + OF_CA2T + k * 28);
#define K8F(Aq, P) { float4 w = W[P]; Aq.x += w.x*xv; Aq.y += w.y*xv; Aq.z += w.z*xv; Aq.w += w.w*xv; }
    K8F(A0,0) K8F(A1,1) K8F(A2,2) K8F(A3,3) K8F(A4,4) K8F(A5,5) K8F(A6,6)
#undef K8F
  }
  float s02 = F[OF_CS02 + q];
  float part = 0.f;
  auto ep = [&](int c, float v) {
    if (c < 25) {
      float zc = fmaxf(v + C.ca2_b[c] * s02 + C.l02_b[q], 0.f);
      part += C.cb2_w[c * 2 + hh] * zc;
    }
  };
#define K8E(Aq, P) { ep(4*P+0, Aq.x); ep(4*P+1, Aq.y); ep(4*P+2, Aq.z); ep(4*P+3, Aq.w); }
  K8E(A0,0) K8E(A1,1) K8E(A2,2) K8E(A3,3) K8E(A4,4) K8E(A5,5) K8E(A6,6)
#undef K8E
  atomicAdd(&C.zAcc[col], C.fl_w[q] * part);
}

// ---------- K8c: out = const + zAcc + yAcc[h]. grid (CB/256, 1) ----------
__global__ __launch_bounds__(256) void k8c(Ctx C) {
  const int col = blockIdx.x * 256 + threadIdx.x;
  if (col >= C.CB) return;
  float scc2 = C.F[OF_CSCC2];
  float cst = C.fl_b[0];
#pragma unroll
  for (int q = 0; q < 10; ++q)
    cst += C.fl_w[q] * (C.cb2_b[0] + C.r02_b[q] * scc2 + C.cc2_b[0]);
  float za = C.zAcc[col];
#pragma unroll
  for (int h = 0; h < 3; ++h)
    C.out[(size_t)(C.b0g + col) * 3 + h] = cst + za + C.yAcc[(size_t)h * C.CB + col];
}

extern "C" void kernel_launch(void* const* d_in, const int* in_sizes, int n_in,
                              void* d_out, int out_size, void* d_ws, size_t ws_size,
                              hipStream_t stream) {
  (void)n_in; (void)out_size;
  Ctx C;
  C.x     = (const float*)d_in[0];
  C.ca1_w = (const float*)d_in[1];  C.ca1_b = (const float*)d_in[2];
  C.l01_w = (const float*)d_in[3];  C.l01_b = (const float*)d_in[4];
  C.cb1_w = (const float*)d_in[5];  C.cb1_b = (const float*)d_in[6];
  C.cc1_w = (const float*)d_in[7];  C.cc1_b = (const float*)d_in[8];
  C.r01_w = (const float*)d_in[9];  C.r01_b = (const float*)d_in[10];
  C.c1_w  = (const float*)d_in[11]; C.c1_b  = (const float*)d_in[12];
  C.l1_w  = (const float*)d_in[13]; C.l1_b  = (const float*)d_in[14];
  C.c2_w  = (const float*)d_in[15]; C.c2_b  = (const float*)d_in[16];
  C.ca_w  = (const float*)d_in[17]; C.ca_b  = (const float*)d_in[18];
  C.ra_w  = (const float*)d_in[19]; C.ra_b  = (const float*)d_in[20];
  C.ca2_w = (const float*)d_in[21]; C.ca2_b = (const float*)d_in[22];
  C.l02_w = (const float*)d_in[23]; C.l02_b = (const float*)d_in[24];
  C.cb2_w = (const float*)d_in[25]; C.cb2_b = (const float*)d_in[26];
  C.cc2_w = (const float*)d_in[27]; C.cc2_b = (const float*)d_in[28];
  C.r02_w = (const float*)d_in[29]; C.r02_b = (const float*)d_in[30];
  C.fl_w  = (const float*)d_in[31]; C.fl_b  = (const float*)d_in[32];
  C.out   = (float*)d_out;

  const int B = in_sizes[0] / 635;

  int CB = 2048;                      // L3-resident chunk (was 4096)
  if (CB > B) CB = B;
  size_t accoff, actoff;
  for (;;) {
    accoff = ((size_t)F32_TOTAL * 4 + 255) & ~(size_t)255;
    actoff = (accoff + (size_t)4 * CB * 4 + 255) & ~(size_t)255;
    if (CB <= 256 || actoff + (size_t)ROWS_TOTAL * CB * 2 <= ws_size) break;
    CB >>= 1;
  }
  C.F = (float*)d_ws;
  C.zAcc = (float*)((char*)d_ws + accoff);
  C.yAcc = C.zAcc + CB;
  C.A = (u16*)((char*)d_ws + actoff);
  C.CB = CB;

  C.b0g = 0;
  k0c<<<dim3(32), dim3(256), 0, stream>>>(C);

  const int bt64 = CB / 64, bt128 = CB / 128, bt256 = (CB + 255) / 256;
  for (int b0 = 0; b0 < B; b0 += CB) {
    C.b0g = b0;
    hipMemsetAsync(C.zAcc, 0, (size_t)4 * CB * sizeof(float), stream);
    k0t<<<dim3(bt64, 10),   dim3(256), 0, stream>>>(C);
    k1 <<<dim3(bt256, 30),  dim3(256), 0, stream>>>(C);
    k2 <<<dim3(bt256, 75),  dim3(256), 0, stream>>>(C);
    k3 <<<dim3(bt256, 60),  dim3(256), 0, stream>>>(C);
    k4 <<<dim3(bt256, 300), dim3(256), 0, stream>>>(C);
    k5 <<<dim3(bt256, 150), dim3(256), 0, stream>>>(C);
    k6m<<<dim3(bt128, 90),  dim3(256), 0, stream>>>(C);
    k7 <<<dim3(bt256, 375), dim3(256), 0, stream>>>(C);
    k8a<<<dim3(bt256, 20),  dim3(256), 0, stream>>>(C);
    k8c<<<dim3(bt256, 1),   dim3(256), 0, stream>>>(C);
  }
}

// Round 16
// 324.829 us; speedup vs baseline: 1.4985x; 1.4985x over previous
//
#include <hip/hip_runtime.h>

// Round 16: revert CB to 4096 (round-14 verified config; chunking falsified).
// k8a parallelism fix: split the 25 c-accumulators across grid.y (hh,q,cg),
// 5 c per block with FULL o-contraction (relu exact); 320 -> 1600 blocks.
// CA2T re-laid-out [k][cg=5][8] (stride 40) for aligned group reads.

typedef unsigned short u16;
typedef __attribute__((ext_vector_type(8))) short bf16x8;
typedef __attribute__((ext_vector_type(4))) float f32x4;
typedef __attribute__((ext_vector_type(8))) unsigned short u16x8;
typedef __attribute__((ext_vector_type(2))) unsigned int u32x2;

__device__ __forceinline__ float bf2f(u16 u) {
  return __uint_as_float(((unsigned)u) << 16);
}
__device__ __forceinline__ u16 f2bf(float f) {
  unsigned u = __float_as_uint(f);
  return (u16)((u + 0x7FFFu + ((u >> 16) & 1u)) >> 16);   // RNE
}

#define Z4 make_float4(0.f, 0.f, 0.f, 0.f)

// ---- fp32 ws region offsets (floats) ----
#define OF_CS01   0        // 81
#define OF_CS1    81       // 30
#define OF_CSR    111      // 30
#define OF_CSAC   141      // 125
#define OF_CS02   266      // 10
#define OF_CSCC2  276      // 1
#define OF_L01T   280      // 127*84  [i][a pad 84]
#define OF_R01T   10948    // 127*84
#define OF_SWT    21616    // 81*64   [a][j2 pad 64]
#define OF_CB1T   26800    // 15*25   [k=c5*3+dh][c]
#define OF_C1T    27175    // 50*75   [k=c*2+dc][m]
#define OF_SCT    30928    // 30*20
#define OF_CA2T   31528    // 250*40  [k][cg=5][8] (5 used of 8)
#define OF_WT2    41528    // u16[128][256] bf16 weights for k6 MFMA
#define OF_ZPAD   57912    // 8 floats of zeros (pad source for global_load_lds)
#define F32_TOTAL 57920

// ---- activation pool (u16 rows, pitch CB), lifetimes overlapped ----
#define R_XT   0      // 635
#define R_XL   635    // 405
#define R_YA   1040   // 405
#define R_ZA   1445   // 2025
#define R_P    3470   // 1500
#define R_Q    4970   // 300   (..5270)
#define R_V4A  5270   // 6000  (1500 ushort4-rows) [K4..K5]
#define R_V1   11270  // 1500  [K4..K5]
#define R_VRP  12770  // 3750  planar v right: [h=0..4][c*30+j] [K4..K6]
#define R_TP   16520  // 9000  planar t: [h=0..3][m*30+j]       [K5..K6]
#define R_X2   0      // 11250 [K6..K7]  rows = (h3*30+j)*125+o
#define R_XJ   12770  // 3750  [K7..K8a]
#define ROWS_TOTAL 25520

struct Ctx {
  const float *x, *ca1_w, *ca1_b, *l01_b, *r01_b, *cb1_b, *cc1_w, *cc1_b;
  const float *c1_b, *l1_b, *c2_b, *ca_b, *ra_b, *ca2_b, *l02_b;
  const float *cb2_w, *cb2_b, *cc2_w, *cc2_b, *r02_b, *fl_w, *fl_b;
  const float *l01_w, *r01_w, *l1_w, *ra_w, *c1_w, *c2_w, *ca_w, *cb1_w;
  const float *l02_w, *r02_w, *ca2_w;
  float *F;
  float *zAcc;      // [CB]
  float *yAcc;      // [3][CB]
  u16 *A;
  float *out;
  int CB;
  int b0g;
};

// ---------- K0C: constants + transposed/padded weights. grid(32) ----------
__global__ __launch_bounds__(256) void k0c(Ctx C) {
  const int t0 = blockIdx.x * 256 + threadIdx.x;
  const int NT = 32 * 256;
  float* F = C.F;
  for (int k = t0; k < 277; k += NT) {
    float s = 0.f;
    if (k < 81)       { for (int i = 0; i < 127; ++i) s += C.l01_w[k * 127 + i]; F[OF_CS01 + k] = s; }
    else if (k < 111) { int j = k - 81;  for (int a = 0; a < 81; ++a) s += C.l1_w[j * 81 + a]; F[OF_CS1 + j] = s; }
    else if (k < 141) { int j = k - 111; for (int a = 0; a < 81; ++a) s += C.ra_w[j * 81 + a]; F[OF_CSR + j] = s; }
    else if (k < 266) { int o = k - 141; for (int i = 0; i < 75; ++i) s += C.ca_w[o * 75 + i]; F[OF_CSAC + o] = s; }
    else if (k < 276) { int q = k - 266; for (int j = 0; j < 30; ++j) s += C.l02_w[q * 30 + j]; F[OF_CS02 + q] = s; }
    else              { float ss = 0.f; for (int o = 0; o < 125; ++o) ss += C.cc2_w[o]; F[OF_CSCC2] = ss; }
  }
  for (int e = t0; e < 8; e += NT) F[OF_ZPAD + e] = 0.f;
  for (int e = t0; e < 10668; e += NT) { int i = e / 84, a = e % 84;
    F[OF_L01T + e] = (a < 81) ? C.l01_w[a * 127 + i] : 0.f; }
  for (int e = t0; e < 10668; e += NT) { int i = e / 84, a = e % 84;
    F[OF_R01T + e] = (a < 81) ? C.r01_w[a * 127 + i] : 0.f; }
  for (int e = t0; e < 5184; e += NT)  { int a = e / 64, j2 = e % 64;
    F[OF_SWT + e] = (j2 < 30) ? C.l1_w[j2 * 81 + a]
                  : (j2 < 60) ? C.ra_w[(j2 - 30) * 81 + a] : 0.f; }
  for (int e = t0; e < 375; e += NT)   { int k = e / 25, c = e % 25; F[OF_CB1T + e] = C.cb1_w[c * 15 + k]; }
  for (int e = t0; e < 3750; e += NT)  { int k = e / 75, m = e % 75; F[OF_C1T + e] = C.c1_w[m * 50 + k]; }
  for (int e = t0; e < 600; e += NT)   { int j = e / 20, q2 = e % 20;
    F[OF_SCT + e] = (q2 < 10) ? C.l02_w[q2 * 30 + j] : C.r02_w[(q2 - 10) * 30 + j]; }
  for (int e = t0; e < 10000; e += NT) { int k = e / 40, r = e % 40, cg = r / 8, i = r % 8;
    F[OF_CA2T + e] = (i < 5) ? C.ca2_w[(cg * 5 + i) * 250 + k] : 0.f; }
  u16* WT2 = (u16*)(F + OF_WT2);
  for (int e = t0; e < 32768; e += NT) {
    int o = e >> 8, k = e & 255;
    float v = 0.f;
    if (o < 125) {
      if (k < 150) v = C.c2_w[o * 150 + k];
      else if (k >= 160 && k < 235) v = C.ca_w[o * 75 + (k - 160)];
    }
    WT2[e] = f2bf(v);
  }
}

// ---------- K0T: transpose x -> xT[635][CB] bf16. grid (CB/64, 10) ----------
__global__ __launch_bounds__(256) void k0t(Ctx C) {
  __shared__ float tile[64][65];
  const int tid = threadIdx.x;
  const int b0 = blockIdx.x * 64;
  const int i0 = blockIdx.y * 64;
  for (int e = tid; e < 64 * 64; e += 256) {
    int s = e >> 6, ii = e & 63, gi = i0 + ii;
    if (gi < 635) tile[s][ii] = C.x[(size_t)(C.b0g + b0 + s) * 635 + gi];
  }
  __syncthreads();
  const int lane = tid & 63, wv = tid >> 6;
  u16* xT = C.A + (size_t)R_XT * C.CB;
#pragma unroll
  for (int k = 0; k < 16; ++k) {
    int r = wv * 16 + k, gi = i0 + r;
    if (gi < 635) xT[(size_t)gi * C.CB + b0 + lane] = f2bf(tile[lane][r]);
  }
}

// ---------- K1: XL = l01*x, yA = r01*x + r01_b. grid (CB/256, 30) ----------
__global__ __launch_bounds__(256) void k1(Ctx C) {
  const int col = blockIdx.x * 256 + threadIdx.x;
  if (col >= C.CB) return;
  const int g = blockIdx.y, type = g / 15, r = g % 15, h = r / 3, a0 = (r % 3) * 28;
  const size_t cb = (size_t)C.CB;
  const u16* __restrict__ xT = C.A + (size_t)R_XT * cb;
  const float* __restrict__ wT = C.F + (type ? OF_R01T : OF_L01T) + a0;
  float4 A0=Z4,A1=Z4,A2=Z4,A3=Z4,A4=Z4,A5=Z4,A6=Z4;
  for (int i = 0; i < 127; ++i) {
    float xv = bf2f(xT[(size_t)(h * 127 + i) * cb + col]);
    const float4* __restrict__ W = (const float4*)(wT + i * 84);
#define K1F(Aq, P) { float4 w = W[P]; Aq.x += w.x*xv; Aq.y += w.y*xv; Aq.z += w.z*xv; Aq.w += w.w*xv; }
    K1F(A0,0) K1F(A1,1) K1F(A2,2) K1F(A3,3) K1F(A4,4) K1F(A5,5) K1F(A6,6)
#undef K1F
  }
  u16* dst = C.A + (size_t)(type ? R_YA : R_XL) * cb;
  auto wr = [&](int a, float v) {
    if (a < 81) {
      float rr = v + (type ? C.r01_b[a] : 0.f);
      dst[(size_t)(h * 81 + a) * cb + col] = f2bf(rr);
    }
  };
#define K1O(Aq, P) { wr(a0+4*P+0, Aq.x); wr(a0+4*P+1, Aq.y); wr(a0+4*P+2, Aq.z); wr(a0+4*P+3, Aq.w); }
  K1O(A0,0) K1O(A1,1) K1O(A2,2) K1O(A3,3) K1O(A4,4) K1O(A5,5) K1O(A6,6)
#undef K1O
}

// ---------- K2: zA = relu(conv_ca1(XL) + ca1_b*S01 + l01_b). grid (CB/256, 75) ----------
__global__ __launch_bounds__(256) void k2(Ctx C) {
  const int col = blockIdx.x * 256 + threadIdx.x;
  if (col >= C.CB) return;
  const int g = blockIdx.y, c5 = g / 15, r = g % 15, h = r / 3, a0 = (r % 3) * 27;
  const u16* __restrict__ XL = C.A + (size_t)R_XL * C.CB;
  const float* __restrict__ F = C.F;
  float acc[27];
  float cb = C.ca1_b[c5];
#pragma unroll
  for (int a = 0; a < 27; ++a) acc[a] = cb * F[OF_CS01 + a0 + a] + C.l01_b[a0 + a];
#pragma unroll
  for (int dh = 0; dh < 3; ++dh) {
    int hp = h - 1 + dh;
    if (hp < 0 || hp > 4) continue;
    float w = C.ca1_w[c5 * 3 + dh];
#pragma unroll
    for (int a = 0; a < 27; ++a) acc[a] += w * bf2f(XL[(size_t)(hp * 81 + a0 + a) * C.CB + col]);
  }
  u16* zA = C.A + (size_t)R_ZA * C.CB;
#pragma unroll
  for (int a = 0; a < 27; ++a)
    zA[(size_t)((c5 * 5 + h) * 81 + a0 + a) * C.CB + col] = f2bf(fmaxf(acc[a], 0.f));
}

// ---------- K3: P = SW*zA, Q = SW*yA. grid (CB/256, 60) ----------
__global__ __launch_bounds__(256) void k3(Ctx C) {
  const int col = blockIdx.x * 256 + threadIdx.x;
  if (col >= C.CB) return;
  const int g = blockIdx.y, pair = g >> 1, j0 = (g & 1) * 32;
  const bool isP = (pair < 25);
  const size_t cb = (size_t)C.CB;
  const u16* __restrict__ src = C.A + (size_t)(isP ? (R_ZA + pair * 81) : (R_YA + (pair - 25) * 81)) * cb;
  const float* __restrict__ SWT = C.F + OF_SWT + j0;
  float4 A0=Z4,A1=Z4,A2=Z4,A3=Z4,A4=Z4,A5=Z4,A6=Z4,A7=Z4;
  for (int a = 0; a < 81; ++a) {
    float xv = bf2f(src[(size_t)a * cb + col]);
    const float4* __restrict__ W = (const float4*)(SWT + a * 64);
#define K3F(Aq, P) { float4 w = W[P]; Aq.x += w.x*xv; Aq.y += w.y*xv; Aq.z += w.z*xv; Aq.w += w.w*xv; }
    K3F(A0,0) K3F(A1,1) K3F(A2,2) K3F(A3,3) K3F(A4,4) K3F(A5,5) K3F(A6,6) K3F(A7,7)
#undef K3F
  }
  u16* dst = C.A + (size_t)(isP ? (R_P + pair * 60) : (R_Q + (pair - 25) * 60)) * cb;
  auto wr = [&](int j2, float v) {
    if (j2 < 60) dst[(size_t)j2 * cb + col] = f2bf(v);
  };
#define K3O(Aq, P) { wr(j0+4*P+0, Aq.x); wr(j0+4*P+1, Aq.y); wr(j0+4*P+2, Aq.z); wr(j0+4*P+3, Aq.w); }
  K3O(A0,0) K3O(A1,1) K3O(A2,2) K3O(A3,3) K3O(A4,4) K3O(A5,5) K3O(A6,6) K3O(A7,7)
#undef K3O
}

// ---------- K4: v packed + planar right-half. grid (CB/256, 300) ----------
__global__ __launch_bounds__(256) void k4(Ctx C) {
  const int col = blockIdx.x * 256 + threadIdx.x;
  if (col >= C.CB) return;
  const int g = blockIdx.y, cg = g / 60, j2 = g % 60;
  const size_t cb = (size_t)C.CB;
  const u16* __restrict__ Pb = C.A + (size_t)R_P * cb;
  const u16* __restrict__ Qb = C.A + (size_t)R_Q * cb;
  const float* __restrict__ F = C.F;
  float sj = (j2 < 30) ? F[OF_CS1 + j2] : F[OF_CSR + (j2 - 30)];
  float acc[5][5];
#pragma unroll
  for (int cl = 0; cl < 5; ++cl) {
    int c = cg * 5 + cl;
    float base = (C.cb1_b[c] + C.cc1_b[c]) * sj;
    float cw = C.cc1_w[c];
#pragma unroll
    for (int h = 0; h < 5; ++h)
      acc[cl][h] = base + cw * bf2f(Qb[(size_t)(h * 60 + j2) * cb + col]);
  }
#pragma unroll
  for (int c5 = 0; c5 < 5; ++c5)
#pragma unroll
    for (int hp = 0; hp < 5; ++hp) {
      float pv = bf2f(Pb[(size_t)((c5 * 5 + hp) * 60 + j2) * cb + col]);
#pragma unroll
      for (int dh = 0; dh < 3; ++dh) {
        int h = hp + 1 - dh;
        if (h < 0 || h > 4) continue;
        const float* __restrict__ w = F + OF_CB1T + (c5 * 3 + dh) * 25 + cg * 5;
#pragma unroll
        for (int cl = 0; cl < 5; ++cl) acc[cl][h] += w[cl] * pv;
      }
    }
  u16* v4 = C.A + (size_t)R_V4A * cb;
  u16* v1 = C.A + (size_t)R_V1 * cb;
#pragma unroll
  for (int cl = 0; cl < 5; ++cl) {
    int row = (cg * 5 + cl) * 60 + j2;
    ushort4 pk;
    pk.x = f2bf(acc[cl][0]); pk.y = f2bf(acc[cl][1]);
    pk.z = f2bf(acc[cl][2]); pk.w = f2bf(acc[cl][3]);
    *(ushort4*)(v4 + ((size_t)row * cb + col) * 4) = pk;
    v1[(size_t)row * cb + col] = f2bf(acc[cl][4]);
  }
  if (j2 >= 30) {
    u16* vrp = C.A + (size_t)R_VRP * cb;
    int jr = j2 - 30;
#pragma unroll
    for (int cl = 0; cl < 5; ++cl) {
      int base = (cg * 5 + cl) * 30 + jr;
      vrp[(size_t)(base)        * cb + col] = f2bf(acc[cl][0]);
      vrp[(size_t)(base + 750)  * cb + col] = f2bf(acc[cl][1]);
      vrp[(size_t)(base + 1500) * cb + col] = f2bf(acc[cl][2]);
      vrp[(size_t)(base + 2250) * cb + col] = f2bf(acc[cl][3]);
      vrp[(size_t)(base + 3000) * cb + col] = f2bf(acc[cl][4]);
    }
  }
}

// ---------- K5: t planar. 15 named float4 (components = h). grid (CB/256, 150) ----------
__global__ __launch_bounds__(256, 2) void k5(Ctx C) {
  const int col = blockIdx.x * 256 + threadIdx.x;
  if (col >= C.CB) return;
  const int g = blockIdx.y, mg = g / 30, j = g % 30;
  const size_t cb = (size_t)C.CB;
  const u16* __restrict__ v4 = C.A + (size_t)R_V4A * cb;
  const u16* __restrict__ v1 = C.A + (size_t)R_V1 * cb;
  const float* __restrict__ F = C.F;
  float s1 = F[OF_CS1 + j], lb = C.l1_b[j];
  float4 B0,B1,B2,B3,B4,B5,B6,B7,B8,B9,B10,B11,B12,B13,B14;
#define K5I(Bq, P) { float bb = C.c1_b[mg*15+P] * s1 + lb; Bq = make_float4(bb,bb,bb,bb); }
  K5I(B0,0) K5I(B1,1) K5I(B2,2) K5I(B3,3) K5I(B4,4) K5I(B5,5) K5I(B6,6) K5I(B7,7)
  K5I(B8,8) K5I(B9,9) K5I(B10,10) K5I(B11,11) K5I(B12,12) K5I(B13,13) K5I(B14,14)
#undef K5I
  for (int c = 0; c < 25; ++c) {
    int row = c * 60 + j;
    ushort4 pk = *(const ushort4*)(v4 + ((size_t)row * cb + col) * 4);
    float x0 = bf2f(pk.x), x1 = bf2f(pk.y), x2 = bf2f(pk.z), x3 = bf2f(pk.w);
    float x4 = bf2f(v1[(size_t)row * cb + col]);
    const float* __restrict__ wp0 = F + OF_C1T + (c * 2) * 75 + mg * 15;
    const float* __restrict__ wp1 = wp0 + 75;
#define K5F(Bq, P) { float w0v = wp0[P], w1v = wp1[P]; \
    Bq.x += w0v*x0 + w1v*x1; Bq.y += w0v*x1 + w1v*x2; \
    Bq.z += w0v*x2 + w1v*x3; Bq.w += w0v*x3 + w1v*x4; }
    K5F(B0,0) K5F(B1,1) K5F(B2,2) K5F(B3,3) K5F(B4,4) K5F(B5,5) K5F(B6,6) K5F(B7,7)
    K5F(B8,8) K5F(B9,9) K5F(B10,10) K5F(B11,11) K5F(B12,12) K5F(B13,13) K5F(B14,14)
#undef K5F
  }
  u16* tp = C.A + (size_t)R_TP * cb;
#define K5O(Bq, P) { int rb = (mg*15+P)*30 + j; \
    tp[(size_t)(rb)        * cb + col] = f2bf(fmaxf(Bq.x, 0.f)); \
    tp[(size_t)(rb + 2250) * cb + col] = f2bf(fmaxf(Bq.y, 0.f)); \
    tp[(size_t)(rb + 4500) * cb + col] = f2bf(fmaxf(Bq.z, 0.f)); \
    tp[(size_t)(rb + 6750) * cb + col] = f2bf(fmaxf(Bq.w, 0.f)); }
  K5O(B0,0) K5O(B1,1) K5O(B2,2) K5O(B3,3) K5O(B4,4) K5O(B5,5) K5O(B6,6) K5O(B7,7)
  K5O(B8,8) K5O(B9,9) K5O(B10,10) K5O(B11,11) K5O(B12,12) K5O(B13,13) K5O(B14,14)
#undef K5O
}

// ---------- K6M: x2 via MFMA; wave = 2 o-tiles x 8 M-tiles, B in regs. grid (CB/128, 90) ----------
union CvtAF { u32x2 p[2]; bf16x8 v; };

#define RD(D, TA, OFF) asm volatile("ds_read_b64_tr_b16 %0, %1 offset:" OFF : "=&v"(D) : "v"(TA));
#define TRS_EVEN(TA) \
  RD(p00,TA,"0")     RD(p01,TA,"1024")  RD(p10,TA,"8192")  RD(p11,TA,"9216") \
  RD(p20,TA,"16384") RD(p21,TA,"17408") RD(p30,TA,"24576") RD(p31,TA,"25600") \
  RD(p40,TA,"32768") RD(p41,TA,"33792") RD(p50,TA,"40960") RD(p51,TA,"41984") \
  RD(p60,TA,"49152") RD(p61,TA,"50176") RD(p70,TA,"57344") RD(p71,TA,"58368")
#define TRS_ODD(TA) \
  RD(p00,TA,"128")   RD(p01,TA,"1152")  RD(p10,TA,"8320")  RD(p11,TA,"9344") \
  RD(p20,TA,"16512") RD(p21,TA,"17536") RD(p30,TA,"24704") RD(p31,TA,"25728") \
  RD(p40,TA,"32896") RD(p41,TA,"33920") RD(p50,TA,"41088") RD(p51,TA,"42112") \
  RD(p60,TA,"49280") RD(p61,TA,"50304") RD(p70,TA,"57472") RD(p71,TA,"58496")

__global__ __launch_bounds__(256, 2) void k6m(Ctx C) {
  __shared__ u16 sA[32768];   // 64 KB
  const int tid = threadIdx.x;
  const int col0 = blockIdx.x * 128;
  const int gy = blockIdx.y;
  const int j = gy / 3, h3 = gy % 3;
  const size_t cb = (size_t)C.CB;
  const u16* __restrict__ A_ = C.A;
  const u16* __restrict__ WT2 = (const u16*)(C.F + OF_WT2);
  const float* __restrict__ F = C.F;

  // ---- stage A-tile via global_load_lds (r11-verified) ----
  const int x = tid & 63, wv = tid >> 6;
  const int klane = (x >> 1) & 3;
  const int m0s = ((x >> 3) << 4) + ((x & 1) << 3);
  const u16* zsrc = (const u16*)(F + OF_ZPAD);
#pragma unroll
  for (int p = 0; p < 16; ++p) {
    int k = p * 16 + wv * 4 + klane;
    const u16* src;
    bool pad = (k >= 150 && k < 160) || (k >= 235);
    if (pad) {
      src = zsrc;
    } else {
      int srow;
      if (k < 150) srow = R_TP + (h3 + (k & 1)) * 2250 + (k >> 1) * 30 + j;
      else { int kk = k - 160; int c = kk / 3; srow = R_VRP + (h3 + (kk - c * 3)) * 750 + c * 30 + j; }
      src = A_ + (size_t)srow * cb + col0 + m0s;
    }
    __builtin_amdgcn_global_load_lds(
        (const __attribute__((address_space(1))) void*)src,
        (__attribute__((address_space(3))) void*)&sA[(p * 4 + wv) * 512],
        16, 0, 0);
  }

  // ---- B-fragments into registers ----
  const int l = tid & 63, w = tid >> 6;
  const int lc = l & 15, q = l >> 4;
  const u16* wbA = WT2 + (size_t)(w * 32 + lc) * 256 + q * 8;
  const u16* wbB = WT2 + (size_t)(w * 32 + 16 + lc) * 256 + q * 8;
  bf16x8 b00 = *(const bf16x8*)(wbA + 0*32), b01 = *(const bf16x8*)(wbA + 1*32),
         b02 = *(const bf16x8*)(wbA + 2*32), b03 = *(const bf16x8*)(wbA + 3*32),
         b04 = *(const bf16x8*)(wbA + 4*32), b05 = *(const bf16x8*)(wbA + 5*32),
         b06 = *(const bf16x8*)(wbA + 6*32), b07 = *(const bf16x8*)(wbA + 7*32);
  bf16x8 b10 = *(const bf16x8*)(wbB + 0*32), b11 = *(const bf16x8*)(wbB + 1*32),
         b12 = *(const bf16x8*)(wbB + 2*32), b13 = *(const bf16x8*)(wbB + 3*32),
         b14 = *(const bf16x8*)(wbB + 4*32), b15 = *(const bf16x8*)(wbB + 5*32),
         b16 = *(const bf16x8*)(wbB + 6*32), b17 = *(const bf16x8*)(wbB + 7*32);

  // ---- per-lane epilogue constants ----
  float rbj = C.ra_b[j];
  u16* x2b = C.A + (size_t)R_X2 * cb;
  const size_t rowbase = (size_t)(h3 * 30 + j) * 125;
  const int o0 = w * 32 + lc;
  const int o1 = o0 + 16;
  const int o1c = (o1 < 125) ? o1 : 0;
  float bs0 = C.c2_b[o0] + C.ca_b[o0] + rbj * F[OF_CSAC + o0];
  float bs1 = C.c2_b[o1c] + C.ca_b[o1c] + rbj * F[OF_CSAC + o1c];

  __syncthreads();

  unsigned ldsbase = (unsigned)(size_t)(&sA[0]);
  const unsigned ta0 = ldsbase + (unsigned)((2 * q) * 1024 + lc * 8);
  const unsigned ta1 = ta0 + 256;
  const unsigned ta2 = ta0 + 512;
  const unsigned ta3 = ta0 + 768;

  u32x2 p00,p01, p10,p11, p20,p21, p30,p31, p40,p41, p50,p51, p60,p61, p70,p71;

  TRS_EVEN(ta0)

#define MM(FS, BA, BB) \
    a0 = __builtin_amdgcn_mfma_f32_16x16x32_bf16(FS, BA, a0, 0, 0, 0); \
    a1 = __builtin_amdgcn_mfma_f32_16x16x32_bf16(FS, BB, a1, 0, 0, 0);

#define MG_BODY(MG, ...) { \
    asm volatile("s_waitcnt lgkmcnt(0)" ::: "memory"); \
    __builtin_amdgcn_sched_barrier(0); \
    bf16x8 f0,f1,f2,f3,f4,f5,f6,f7; \
    { CvtAF c_; c_.p[0]=p00; c_.p[1]=p01; f0=c_.v; } \
    { CvtAF c_; c_.p[0]=p10; c_.p[1]=p11; f1=c_.v; } \
    { CvtAF c_; c_.p[0]=p20; c_.p[1]=p21; f2=c_.v; } \
    { CvtAF c_; c_.p[0]=p30; c_.p[1]=p31; f3=c_.v; } \
    { CvtAF c_; c_.p[0]=p40; c_.p[1]=p41; f4=c_.v; } \
    { CvtAF c_; c_.p[0]=p50; c_.p[1]=p51; f5=c_.v; } \
    { CvtAF c_; c_.p[0]=p60; c_.p[1]=p61; f6=c_.v; } \
    { CvtAF c_; c_.p[0]=p70; c_.p[1]=p71; f7=c_.v; } \
    __VA_ARGS__ \
    f32x4 a0 = {0.f,0.f,0.f,0.f}, a1 = {0.f,0.f,0.f,0.f}; \
    MM(f0,b00,b10) MM(f1,b01,b11) MM(f2,b02,b12) MM(f3,b03,b13) \
    MM(f4,b04,b14) MM(f5,b05,b15) MM(f6,b06,b16) MM(f7,b07,b17) \
    const int cw = col0 + (MG) * 16 + q * 4; \
    { ushort4 pk; pk.x = f2bf(a0[0]+bs0); pk.y = f2bf(a0[1]+bs0); \
      pk.z = f2bf(a0[2]+bs0); pk.w = f2bf(a0[3]+bs0); \
      *(ushort4*)(x2b + (rowbase + o0) * cb + cw) = pk; } \
    if (o1 < 125) { ushort4 pk; pk.x = f2bf(a1[0]+bs1); pk.y = f2bf(a1[1]+bs1); \
      pk.z = f2bf(a1[2]+bs1); pk.w = f2bf(a1[3]+bs1); \
      *(ushort4*)(x2b + (rowbase + o1) * cb + cw) = pk; } \
  }

  MG_BODY(0, TRS_ODD(ta0))
  MG_BODY(1, TRS_EVEN(ta1))
  MG_BODY(2, TRS_ODD(ta1))
  MG_BODY(3, TRS_EVEN(ta2))
  MG_BODY(4, TRS_ODD(ta2))
  MG_BODY(5, TRS_EVEN(ta3))
  MG_BODY(6, TRS_ODD(ta3))
  MG_BODY(7)
#undef MG_BODY
#undef MM
}

// ---------- K7: XJ_left + fold right into yAcc. grid (CB/256, 375) ----------
__global__ __launch_bounds__(256) void k7(Ctx C) {
  const int col = blockIdx.x * 256 + threadIdx.x;
  if (col >= C.CB) return;
  const int g = blockIdx.y;               // g = o*3 + h3
  const int o = g / 3, h3 = g % 3;
  const size_t cb = (size_t)C.CB;
  const u16* __restrict__ x2b = C.A + (size_t)R_X2 * cb;
  const float* __restrict__ SCT = C.F + OF_SCT;
  float4 A0=Z4,A1=Z4,A2=Z4,A3=Z4,A4=Z4;
  for (int j = 0; j < 30; ++j) {
    float xv = bf2f(x2b[(size_t)((h3 * 30 + j) * 125 + o) * cb + col]);
    const float4* __restrict__ W = (const float4*)(SCT + j * 20);
#define K7F(Aq, P) { float4 w = W[P]; Aq.x += w.x*xv; Aq.y += w.y*xv; Aq.z += w.z*xv; Aq.w += w.w*xv; }
    K7F(A0,0) K7F(A1,1) K7F(A2,2) K7F(A3,3) K7F(A4,4)
#undef K7F
  }
  u16* XJ = C.A + (size_t)R_XJ * cb;
  auto wq = [&](int qq, float v) { XJ[(size_t)(g * 10 + qq) * cb + col] = f2bf(v); };
  wq(0,A0.x); wq(1,A0.y); wq(2,A0.z); wq(3,A0.w);
  wq(4,A1.x); wq(5,A1.y); wq(6,A1.z); wq(7,A1.w);
  wq(8,A2.x); wq(9,A2.y);
  float s = C.fl_w[0]*A2.z + C.fl_w[1]*A2.w
          + C.fl_w[2]*A3.x + C.fl_w[3]*A3.y + C.fl_w[4]*A3.z + C.fl_w[5]*A3.w
          + C.fl_w[6]*A4.x + C.fl_w[7]*A4.y + C.fl_w[8]*A4.z + C.fl_w[9]*A4.w;
  atomicAdd(&C.yAcc[(size_t)h3 * C.CB + col], C.cc2_w[o] * s);
}

// ---------- K8a: 5 c per block, full o-contraction; fold cb2+fl into zAcc. grid (CB/256, 100) ----------
__global__ __launch_bounds__(256) void k8a(Ctx C) {
  const int col = blockIdx.x * 256 + threadIdx.x;
  if (col >= C.CB) return;
  const int g = blockIdx.y, cg = g / 20, rem = g % 20, hh = rem / 10, q = rem % 10;
  const size_t cb = (size_t)C.CB;
  const u16* __restrict__ XJ = C.A + (size_t)R_XJ * cb;
  const float* __restrict__ F = C.F;
  float4 A0 = Z4; float a4 = 0.f;
  const float* __restrict__ Wb = F + OF_CA2T + cg * 8;
  for (int k = 0; k < 250; ++k) {
    int o = k >> 1, dh = k & 1;
    float xv = bf2f(XJ[(size_t)((o * 3 + hh + dh) * 10 + q) * cb + col]);
    const float* __restrict__ wr = Wb + k * 40;
    float4 w0 = *(const float4*)wr;
    float w4 = wr[4];
    A0.x += w0.x * xv; A0.y += w0.y * xv; A0.z += w0.z * xv; A0.w += w0.w * xv;
    a4 += w4 * xv;
  }
  float s02 = F[OF_CS02 + q];
  float lb = C.l02_b[q];
  const int c0 = cg * 5;
  float part = 0.f;
  {
    float zc;
    zc = fmaxf(A0.x + C.ca2_b[c0+0] * s02 + lb, 0.f); part += C.cb2_w[(c0+0)*2+hh] * zc;
    zc = fmaxf(A0.y + C.ca2_b[c0+1] * s02 + lb, 0.f); part += C.cb2_w[(c0+1)*2+hh] * zc;
    zc = fmaxf(A0.z + C.ca2_b[c0+2] * s02 + lb, 0.f); part += C.cb2_w[(c0+2)*2+hh] * zc;
    zc = fmaxf(A0.w + C.ca2_b[c0+3] * s02 + lb, 0.f); part += C.cb2_w[(c0+3)*2+hh] * zc;
    zc = fmaxf(a4   + C.ca2_b[c0+4] * s02 + lb, 0.f); part += C.cb2_w[(c0+4)*2+hh] * zc;
  }
  atomicAdd(&C.zAcc[col], C.fl_w[q] * part);
}

// ---------- K8c: out = const + zAcc + yAcc[h]. grid (CB/256, 1) ----------
__global__ __launch_bounds__(256) void k8c(Ctx C) {
  const int col = blockIdx.x * 256 + threadIdx.x;
  if (col >= C.CB) return;
  float scc2 = C.F[OF_CSCC2];
  float cst = C.fl_b[0];
#pragma unroll
  for (int q = 0; q < 10; ++q)
    cst += C.fl_w[q] * (C.cb2_b[0] + C.r02_b[q] * scc2 + C.cc2_b[0]);
  float za = C.zAcc[col];
#pragma unroll
  for (int h = 0; h < 3; ++h)
    C.out[(size_t)(C.b0g + col) * 3 + h] = cst + za + C.yAcc[(size_t)h * C.CB + col];
}

extern "C" void kernel_launch(void* const* d_in, const int* in_sizes, int n_in,
                              void* d_out, int out_size, void* d_ws, size_t ws_size,
                              hipStream_t stream) {
  (void)n_in; (void)out_size;
  Ctx C;
  C.x     = (const float*)d_in[0];
  C.ca1_w = (const float*)d_in[1];  C.ca1_b = (const float*)d_in[2];
  C.l01_w = (const float*)d_in[3];  C.l01_b = (const float*)d_in[4];
  C.cb1_w = (const float*)d_in[5];  C.cb1_b = (const float*)d_in[6];
  C.cc1_w = (const float*)d_in[7];  C.cc1_b = (const float*)d_in[8];
  C.r01_w = (const float*)d_in[9];  C.r01_b = (const float*)d_in[10];
  C.c1_w  = (const float*)d_in[11]; C.c1_b  = (const float*)d_in[12];
  C.l1_w  = (const float*)d_in[13]; C.l1_b  = (const float*)d_in[14];
  C.c2_w  = (const float*)d_in[15]; C.c2_b  = (const float*)d_in[16];
  C.ca_w  = (const float*)d_in[17]; C.ca_b  = (const float*)d_in[18];
  C.ra_w  = (const float*)d_in[19]; C.ra_b  = (const float*)d_in[20];
  C.ca2_w = (const float*)d_in[21]; C.ca2_b = (const float*)d_in[22];
  C.l02_w = (const float*)d_in[23]; C.l02_b = (const float*)d_in[24];
  C.cb2_w = (const float*)d_in[25]; C.cb2_b = (const float*)d_in[26];
  C.cc2_w = (const float*)d_in[27]; C.cc2_b = (const float*)d_in[28];
  C.r02_w = (const float*)d_in[29]; C.r02_b = (const float*)d_in[30];
  C.fl_w  = (const float*)d_in[31]; C.fl_b  = (const float*)d_in[32];
  C.out   = (float*)d_out;

  const int B = in_sizes[0] / 635;

  int CB = 4096;
  if (CB > B) CB = B;
  size_t accoff, actoff;
  for (;;) {
    accoff = ((size_t)F32_TOTAL * 4 + 255) & ~(size_t)255;
    actoff = (accoff + (size_t)4 * CB * 4 + 255) & ~(size_t)255;
    if (CB <= 256 || actoff + (size_t)ROWS_TOTAL * CB * 2 <= ws_size) break;
    CB >>= 1;
  }
  C.F = (float*)d_ws;
  C.zAcc = (float*)((char*)d_ws + accoff);
  C.yAcc = C.zAcc + CB;
  C.A = (u16*)((char*)d_ws + actoff);
  C.CB = CB;

  C.b0g = 0;
  k0c<<<dim3(32), dim3(256), 0, stream>>>(C);

  const int bt64 = CB / 64, bt128 = CB / 128, bt256 = (CB + 255) / 256;
  for (int b0 = 0; b0 < B; b0 += CB) {
    C.b0g = b0;
    hipMemsetAsync(C.zAcc, 0, (size_t)4 * CB * sizeof(float), stream);
    k0t<<<dim3(bt64, 10),   dim3(256), 0, stream>>>(C);
    k1 <<<dim3(bt256, 30),  dim3(256), 0, stream>>>(C);
    k2 <<<dim3(bt256, 75),  dim3(256), 0, stream>>>(C);
    k3 <<<dim3(bt256, 60),  dim3(256), 0, stream>>>(C);
    k4 <<<dim3(bt256, 300), dim3(256), 0, stream>>>(C);
    k5 <<<dim3(bt256, 150), dim3(256), 0, stream>>>(C);
    k6m<<<dim3(bt128, 90),  dim3(256), 0, stream>>>(C);
    k7 <<<dim3(bt256, 375), dim3(256), 0, stream>>>(C);
    k8a<<<dim3(bt256, 100), dim3(256), 0, stream>>>(C);
    k8c<<<dim3(bt256, 1),   dim3(256), 0, stream>>>(C);
  }
}

// Round 17
// 303.481 us; speedup vs baseline: 1.6040x; 1.0703x over previous
//
#include <hip/hip_runtime.h>

// Round 17: k5 moved to MFMA (k5m), reusing the r11/r14-VERIFIED k6m machinery
// (staging permutation, tr-read address pattern, B-in-regs, D-mapping) with
// K=64, N=80(75 used), per-block A = [64k][128cols] (16KB LDS).
// k4 now emits planar LEFT v (R_VLP) instead of packed v4/v1. c1_w -> bf16
// table C1W2[80][64]. Everything else = round 16 (passed, 324.8us).

typedef unsigned short u16;
typedef __attribute__((ext_vector_type(8))) short bf16x8;
typedef __attribute__((ext_vector_type(4))) float f32x4;
typedef __attribute__((ext_vector_type(8))) unsigned short u16x8;
typedef __attribute__((ext_vector_type(2))) unsigned int u32x2;

__device__ __forceinline__ float bf2f(u16 u) {
  return __uint_as_float(((unsigned)u) << 16);
}
__device__ __forceinline__ u16 f2bf(float f) {
  unsigned u = __float_as_uint(f);
  return (u16)((u + 0x7FFFu + ((u >> 16) & 1u)) >> 16);   // RNE
}

#define Z4 make_float4(0.f, 0.f, 0.f, 0.f)

// ---- fp32 ws region offsets (floats) ----
#define OF_CS01   0        // 81
#define OF_CS1    81       // 30
#define OF_CSR    111      // 30
#define OF_CSAC   141      // 125
#define OF_CS02   266      // 10
#define OF_CSCC2  276      // 1
#define OF_L01T   280      // 127*84  [i][a pad 84]
#define OF_R01T   10948    // 127*84
#define OF_SWT    21616    // 81*64   [a][j2 pad 64]
#define OF_CB1T   26800    // 15*25   [k=c5*3+dh][c]
#define OF_C1T    27175    // 50*75   (legacy, unused)
#define OF_SCT    30928    // 30*20
#define OF_CA2T   31528    // 250*40  [k][cg=5][8]
#define OF_WT2    41528    // u16[128][256] bf16 weights for k6 MFMA
#define OF_ZPAD   57912    // 8 floats of zeros
#define OF_C1W2   57920    // u16[80][64] bf16 weights for k5 MFMA (2560 floats)
#define F32_TOTAL 60480

// ---- activation pool (u16 rows, pitch CB), lifetimes overlapped ----
#define R_XT   0      // 635
#define R_XL   635    // 405
#define R_YA   1040   // 405
#define R_ZA   1445   // 2025
#define R_P    3470   // 1500
#define R_Q    4970   // 300   (..5270)
#define R_VLP  5270   // 3750  planar v left:  [h=0..4][c*30+j] [K4..K5m]
#define R_VRP  12770  // 3750  planar v right: [h=0..4][c*30+j] [K4..K6]
#define R_TP   16520  // 9000  planar t: [h=0..3][m*30+j]       [K5m..K6]
#define R_X2   0      // 11250 [K6..K7]  rows = (h3*30+j)*125+o
#define R_XJ   12770  // 3750  [K7..K8a]
#define ROWS_TOTAL 25520

struct Ctx {
  const float *x, *ca1_w, *ca1_b, *l01_b, *r01_b, *cb1_b, *cc1_w, *cc1_b;
  const float *c1_b, *l1_b, *c2_b, *ca_b, *ra_b, *ca2_b, *l02_b;
  const float *cb2_w, *cb2_b, *cc2_w, *cc2_b, *r02_b, *fl_w, *fl_b;
  const float *l01_w, *r01_w, *l1_w, *ra_w, *c1_w, *c2_w, *ca_w, *cb1_w;
  const float *l02_w, *r02_w, *ca2_w;
  float *F;
  float *zAcc;      // [CB]
  float *yAcc;      // [3][CB]
  u16 *A;
  float *out;
  int CB;
  int b0g;
};

// ---------- K0C: constants + transposed/padded weights. grid(32) ----------
__global__ __launch_bounds__(256) void k0c(Ctx C) {
  const int t0 = blockIdx.x * 256 + threadIdx.x;
  const int NT = 32 * 256;
  float* F = C.F;
  for (int k = t0; k < 277; k += NT) {
    float s = 0.f;
    if (k < 81)       { for (int i = 0; i < 127; ++i) s += C.l01_w[k * 127 + i]; F[OF_CS01 + k] = s; }
    else if (k < 111) { int j = k - 81;  for (int a = 0; a < 81; ++a) s += C.l1_w[j * 81 + a]; F[OF_CS1 + j] = s; }
    else if (k < 141) { int j = k - 111; for (int a = 0; a < 81; ++a) s += C.ra_w[j * 81 + a]; F[OF_CSR + j] = s; }
    else if (k < 266) { int o = k - 141; for (int i = 0; i < 75; ++i) s += C.ca_w[o * 75 + i]; F[OF_CSAC + o] = s; }
    else if (k < 276) { int q = k - 266; for (int j = 0; j < 30; ++j) s += C.l02_w[q * 30 + j]; F[OF_CS02 + q] = s; }
    else              { float ss = 0.f; for (int o = 0; o < 125; ++o) ss += C.cc2_w[o]; F[OF_CSCC2] = ss; }
  }
  for (int e = t0; e < 8; e += NT) F[OF_ZPAD + e] = 0.f;
  for (int e = t0; e < 10668; e += NT) { int i = e / 84, a = e % 84;
    F[OF_L01T + e] = (a < 81) ? C.l01_w[a * 127 + i] : 0.f; }
  for (int e = t0; e < 10668; e += NT) { int i = e / 84, a = e % 84;
    F[OF_R01T + e] = (a < 81) ? C.r01_w[a * 127 + i] : 0.f; }
  for (int e = t0; e < 5184; e += NT)  { int a = e / 64, j2 = e % 64;
    F[OF_SWT + e] = (j2 < 30) ? C.l1_w[j2 * 81 + a]
                  : (j2 < 60) ? C.ra_w[(j2 - 30) * 81 + a] : 0.f; }
  for (int e = t0; e < 375; e += NT)   { int k = e / 25, c = e % 25; F[OF_CB1T + e] = C.cb1_w[c * 15 + k]; }
  for (int e = t0; e < 600; e += NT)   { int j = e / 20, q2 = e % 20;
    F[OF_SCT + e] = (q2 < 10) ? C.l02_w[q2 * 30 + j] : C.r02_w[(q2 - 10) * 30 + j]; }
  for (int e = t0; e < 10000; e += NT) { int k = e / 40, r = e % 40, cg = r / 8, i = r % 8;
    F[OF_CA2T + e] = (i < 5) ? C.ca2_w[(cg * 5 + i) * 250 + k] : 0.f; }
  u16* WT2 = (u16*)(F + OF_WT2);
  for (int e = t0; e < 32768; e += NT) {
    int o = e >> 8, k = e & 255;
    float v = 0.f;
    if (o < 125) {
      if (k < 150) v = C.c2_w[o * 150 + k];
      else if (k >= 160 && k < 235) v = C.ca_w[o * 75 + (k - 160)];
    }
    WT2[e] = f2bf(v);
  }
  u16* C1W2 = (u16*)(F + OF_C1W2);
  for (int e = t0; e < 5120; e += NT) {
    int o = e >> 6, k = e & 63;
    float v = (o < 75 && k < 50) ? C.c1_w[o * 50 + k] : 0.f;
    C1W2[e] = f2bf(v);
  }
}

// ---------- K0T: transpose x -> xT[635][CB] bf16. grid (CB/64, 10) ----------
__global__ __launch_bounds__(256) void k0t(Ctx C) {
  __shared__ float tile[64][65];
  const int tid = threadIdx.x;
  const int b0 = blockIdx.x * 64;
  const int i0 = blockIdx.y * 64;
  for (int e = tid; e < 64 * 64; e += 256) {
    int s = e >> 6, ii = e & 63, gi = i0 + ii;
    if (gi < 635) tile[s][ii] = C.x[(size_t)(C.b0g + b0 + s) * 635 + gi];
  }
  __syncthreads();
  const int lane = tid & 63, wv = tid >> 6;
  u16* xT = C.A + (size_t)R_XT * C.CB;
#pragma unroll
  for (int k = 0; k < 16; ++k) {
    int r = wv * 16 + k, gi = i0 + r;
    if (gi < 635) xT[(size_t)gi * C.CB + b0 + lane] = f2bf(tile[lane][r]);
  }
}

// ---------- K1: XL = l01*x, yA = r01*x + r01_b. grid (CB/256, 30) ----------
__global__ __launch_bounds__(256) void k1(Ctx C) {
  const int col = blockIdx.x * 256 + threadIdx.x;
  if (col >= C.CB) return;
  const int g = blockIdx.y, type = g / 15, r = g % 15, h = r / 3, a0 = (r % 3) * 28;
  const size_t cb = (size_t)C.CB;
  const u16* __restrict__ xT = C.A + (size_t)R_XT * cb;
  const float* __restrict__ wT = C.F + (type ? OF_R01T : OF_L01T) + a0;
  float4 A0=Z4,A1=Z4,A2=Z4,A3=Z4,A4=Z4,A5=Z4,A6=Z4;
  for (int i = 0; i < 127; ++i) {
    float xv = bf2f(xT[(size_t)(h * 127 + i) * cb + col]);
    const float4* __restrict__ W = (const float4*)(wT + i * 84);
#define K1F(Aq, P) { float4 w = W[P]; Aq.x += w.x*xv; Aq.y += w.y*xv; Aq.z += w.z*xv; Aq.w += w.w*xv; }
    K1F(A0,0) K1F(A1,1) K1F(A2,2) K1F(A3,3) K1F(A4,4) K1F(A5,5) K1F(A6,6)
#undef K1F
  }
  u16* dst = C.A + (size_t)(type ? R_YA : R_XL) * cb;
  auto wr = [&](int a, float v) {
    if (a < 81) {
      float rr = v + (type ? C.r01_b[a] : 0.f);
      dst[(size_t)(h * 81 + a) * cb + col] = f2bf(rr);
    }
  };
#define K1O(Aq, P) { wr(a0+4*P+0, Aq.x); wr(a0+4*P+1, Aq.y); wr(a0+4*P+2, Aq.z); wr(a0+4*P+3, Aq.w); }
  K1O(A0,0) K1O(A1,1) K1O(A2,2) K1O(A3,3) K1O(A4,4) K1O(A5,5) K1O(A6,6)
#undef K1O
}

// ---------- K2: zA = relu(conv_ca1(XL) + ca1_b*S01 + l01_b). grid (CB/256, 75) ----------
__global__ __launch_bounds__(256) void k2(Ctx C) {
  const int col = blockIdx.x * 256 + threadIdx.x;
  if (col >= C.CB) return;
  const int g = blockIdx.y, c5 = g / 15, r = g % 15, h = r / 3, a0 = (r % 3) * 27;
  const u16* __restrict__ XL = C.A + (size_t)R_XL * C.CB;
  const float* __restrict__ F = C.F;
  float acc[27];
  float cb = C.ca1_b[c5];
#pragma unroll
  for (int a = 0; a < 27; ++a) acc[a] = cb * F[OF_CS01 + a0 + a] + C.l01_b[a0 + a];
#pragma unroll
  for (int dh = 0; dh < 3; ++dh) {
    int hp = h - 1 + dh;
    if (hp < 0 || hp > 4) continue;
    float w = C.ca1_w[c5 * 3 + dh];
#pragma unroll
    for (int a = 0; a < 27; ++a) acc[a] += w * bf2f(XL[(size_t)(hp * 81 + a0 + a) * C.CB + col]);
  }
  u16* zA = C.A + (size_t)R_ZA * C.CB;
#pragma unroll
  for (int a = 0; a < 27; ++a)
    zA[(size_t)((c5 * 5 + h) * 81 + a0 + a) * C.CB + col] = f2bf(fmaxf(acc[a], 0.f));
}

// ---------- K3: P = SW*zA, Q = SW*yA. grid (CB/256, 60) ----------
__global__ __launch_bounds__(256) void k3(Ctx C) {
  const int col = blockIdx.x * 256 + threadIdx.x;
  if (col >= C.CB) return;
  const int g = blockIdx.y, pair = g >> 1, j0 = (g & 1) * 32;
  const bool isP = (pair < 25);
  const size_t cb = (size_t)C.CB;
  const u16* __restrict__ src = C.A + (size_t)(isP ? (R_ZA + pair * 81) : (R_YA + (pair - 25) * 81)) * cb;
  const float* __restrict__ SWT = C.F + OF_SWT + j0;
  float4 A0=Z4,A1=Z4,A2=Z4,A3=Z4,A4=Z4,A5=Z4,A6=Z4,A7=Z4;
  for (int a = 0; a < 81; ++a) {
    float xv = bf2f(src[(size_t)a * cb + col]);
    const float4* __restrict__ W = (const float4*)(SWT + a * 64);
#define K3F(Aq, P) { float4 w = W[P]; Aq.x += w.x*xv; Aq.y += w.y*xv; Aq.z += w.z*xv; Aq.w += w.w*xv; }
    K3F(A0,0) K3F(A1,1) K3F(A2,2) K3F(A3,3) K3F(A4,4) K3F(A5,5) K3F(A6,6) K3F(A7,7)
#undef K3F
  }
  u16* dst = C.A + (size_t)(isP ? (R_P + pair * 60) : (R_Q + (pair - 25) * 60)) * cb;
  auto wr = [&](int j2, float v) {
    if (j2 < 60) dst[(size_t)j2 * cb + col] = f2bf(v);
  };
#define K3O(Aq, P) { wr(j0+4*P+0, Aq.x); wr(j0+4*P+1, Aq.y); wr(j0+4*P+2, Aq.z); wr(j0+4*P+3, Aq.w); }
  K3O(A0,0) K3O(A1,1) K3O(A2,2) K3O(A3,3) K3O(A4,4) K3O(A5,5) K3O(A6,6) K3O(A7,7)
#undef K3O
}

// ---------- K4: v -> planar left (VLP) / planar right (VRP). grid (CB/256, 300) ----------
__global__ __launch_bounds__(256) void k4(Ctx C) {
  const int col = blockIdx.x * 256 + threadIdx.x;
  if (col >= C.CB) return;
  const int g = blockIdx.y, cg = g / 60, j2 = g % 60;
  const size_t cb = (size_t)C.CB;
  const u16* __restrict__ Pb = C.A + (size_t)R_P * cb;
  const u16* __restrict__ Qb = C.A + (size_t)R_Q * cb;
  const float* __restrict__ F = C.F;
  float sj = (j2 < 30) ? F[OF_CS1 + j2] : F[OF_CSR + (j2 - 30)];
  float acc[5][5];
#pragma unroll
  for (int cl = 0; cl < 5; ++cl) {
    int c = cg * 5 + cl;
    float base = (C.cb1_b[c] + C.cc1_b[c]) * sj;
    float cw = C.cc1_w[c];
#pragma unroll
    for (int h = 0; h < 5; ++h)
      acc[cl][h] = base + cw * bf2f(Qb[(size_t)(h * 60 + j2) * cb + col]);
  }
#pragma unroll
  for (int c5 = 0; c5 < 5; ++c5)
#pragma unroll
    for (int hp = 0; hp < 5; ++hp) {
      float pv = bf2f(Pb[(size_t)((c5 * 5 + hp) * 60 + j2) * cb + col]);
#pragma unroll
      for (int dh = 0; dh < 3; ++dh) {
        int h = hp + 1 - dh;
        if (h < 0 || h > 4) continue;
        const float* __restrict__ w = F + OF_CB1T + (c5 * 3 + dh) * 25 + cg * 5;
#pragma unroll
        for (int cl = 0; cl < 5; ++cl) acc[cl][h] += w[cl] * pv;
      }
    }
  if (j2 < 30) {
    u16* vlp = C.A + (size_t)R_VLP * cb;
#pragma unroll
    for (int cl = 0; cl < 5; ++cl) {
      int base = (cg * 5 + cl) * 30 + j2;
#pragma unroll
      for (int h = 0; h < 5; ++h)
        vlp[(size_t)(base + h * 750) * cb + col] = f2bf(acc[cl][h]);
    }
  } else {
    u16* vrp = C.A + (size_t)R_VRP * cb;
    int jr = j2 - 30;
#pragma unroll
    for (int cl = 0; cl < 5; ++cl) {
      int base = (cg * 5 + cl) * 30 + jr;
#pragma unroll
      for (int h = 0; h < 5; ++h)
        vrp[(size_t)(base + h * 750) * cb + col] = f2bf(acc[cl][h]);
    }
  }
}

union CvtAF { u32x2 p[2]; bf16x8 v; };

// ---------- K5M: t via MFMA. wave = 2 M-tiles x 5 o-tiles, K=64. grid (CB/128, 120) ----------
// LDS: byte(k,m) = (k>>2)*1024 + (m>>4)*128 + (k&3)*32 + (m&15)*2  (16KB).
// Staging/tr-read/D-mapping identical to the verified k6m pattern.
__global__ __launch_bounds__(256, 2) void k5m(Ctx C) {
  __shared__ u16 sA[8192];   // 16 KB
  const int tid = threadIdx.x;
  const int col0 = blockIdx.x * 128;
  const int gy = blockIdx.y;          // j*4 + h4
  const int j = gy >> 2, h4 = gy & 3;
  const size_t cb = (size_t)C.CB;
  const u16* __restrict__ A_ = C.A;
  const u16* __restrict__ WB = (const u16*)(C.F + OF_C1W2);
  const float* __restrict__ F = C.F;

  const int x = tid & 63, wv = tid >> 6;
  const int klane = (x >> 1) & 3;
  const int m0s = ((x >> 3) << 4) + ((x & 1) << 3);
  const u16* zsrc = (const u16*)(F + OF_ZPAD);
#pragma unroll
  for (int p = 0; p < 4; ++p) {
    int k = p * 16 + wv * 4 + klane;
    const u16* src;
    if (k >= 50) {
      src = zsrc;
    } else {
      int c = k >> 1, dc = k & 1;
      int srow = R_VLP + (h4 + dc) * 750 + c * 30 + j;
      src = A_ + (size_t)srow * cb + col0 + m0s;
    }
    __builtin_amdgcn_global_load_lds(
        (const __attribute__((address_space(1))) void*)src,
        (__attribute__((address_space(3))) void*)&sA[(p * 4 + wv) * 512],
        16, 0, 0);
  }

  const int l = tid & 63, w = tid >> 6;
  const int lc = l & 15, q = l >> 4;
#define BF(N, S) (*(const bf16x8*)(WB + (size_t)((N)*16 + lc) * 64 + (S)*32 + q*8))
  bf16x8 B00 = BF(0,0), B10 = BF(1,0), B20 = BF(2,0), B30 = BF(3,0), B40 = BF(4,0);
  bf16x8 B01 = BF(0,1), B11 = BF(1,1), B21 = BF(2,1), B31 = BF(3,1), B41 = BF(4,1);
#undef BF
  float s1 = F[OF_CS1 + j], lb = C.l1_b[j];
  const int o4r = 64 + lc;
  const int o4c = (o4r < 75) ? o4r : 0;
  float bs0 = C.c1_b[lc] * s1 + lb;
  float bs1 = C.c1_b[16 + lc] * s1 + lb;
  float bs2 = C.c1_b[32 + lc] * s1 + lb;
  float bs3 = C.c1_b[48 + lc] * s1 + lb;
  float bs4 = C.c1_b[o4c] * s1 + lb;

  __syncthreads();

  unsigned ldsbase = (unsigned)(size_t)(&sA[0]);
  unsigned ta = ldsbase + (unsigned)((2 * q) * 1024 + w * 256 + lc * 8);

  u32x2 e00,e01,e02,e03, e10,e11,e12,e13;
  asm volatile("ds_read_b64_tr_b16 %0, %1"             : "=&v"(e00) : "v"(ta));
  asm volatile("ds_read_b64_tr_b16 %0, %1 offset:1024" : "=&v"(e01) : "v"(ta));
  asm volatile("ds_read_b64_tr_b16 %0, %1 offset:8192" : "=&v"(e02) : "v"(ta));
  asm volatile("ds_read_b64_tr_b16 %0, %1 offset:9216" : "=&v"(e03) : "v"(ta));
  asm volatile("ds_read_b64_tr_b16 %0, %1 offset:128"  : "=&v"(e10) : "v"(ta));
  asm volatile("ds_read_b64_tr_b16 %0, %1 offset:1152" : "=&v"(e11) : "v"(ta));
  asm volatile("ds_read_b64_tr_b16 %0, %1 offset:8320" : "=&v"(e12) : "v"(ta));
  asm volatile("ds_read_b64_tr_b16 %0, %1 offset:9344" : "=&v"(e13) : "v"(ta));
  asm volatile("s_waitcnt lgkmcnt(0)" ::: "memory");
  __builtin_amdgcn_sched_barrier(0);

  bf16x8 f0s0, f0s1, f1s0, f1s1;
  { CvtAF c_; c_.p[0]=e00; c_.p[1]=e01; f0s0=c_.v; }
  { CvtAF c_; c_.p[0]=e02; c_.p[1]=e03; f0s1=c_.v; }
  { CvtAF c_; c_.p[0]=e10; c_.p[1]=e11; f1s0=c_.v; }
  { CvtAF c_; c_.p[0]=e12; c_.p[1]=e13; f1s1=c_.v; }

  f32x4 a00={0,0,0,0},a01={0,0,0,0},a02={0,0,0,0},a03={0,0,0,0},a04={0,0,0,0};
  f32x4 a10={0,0,0,0},a11={0,0,0,0},a12={0,0,0,0},a13={0,0,0,0},a14={0,0,0,0};
#define MF(AC, FA, BB) AC = __builtin_amdgcn_mfma_f32_16x16x32_bf16(FA, BB, AC, 0, 0, 0);
  MF(a00,f0s0,B00) MF(a01,f0s0,B10) MF(a02,f0s0,B20) MF(a03,f0s0,B30) MF(a04,f0s0,B40)
  MF(a10,f1s0,B00) MF(a11,f1s0,B10) MF(a12,f1s0,B20) MF(a13,f1s0,B30) MF(a14,f1s0,B40)
  MF(a00,f0s1,B01) MF(a01,f0s1,B11) MF(a02,f0s1,B21) MF(a03,f0s1,B31) MF(a04,f0s1,B41)
  MF(a10,f1s1,B01) MF(a11,f1s1,B11) MF(a12,f1s1,B21) MF(a13,f1s1,B31) MF(a14,f1s1,B41)
#undef MF

  u16* tp = C.A + (size_t)R_TP * cb;
  const int cw0 = col0 + 2 * w * 16 + q * 4;
#define ST(AC, O, BS, CW) { int o_ = (O); if (o_ < 75) { \
    size_t rw = (size_t)(h4 * 2250 + o_ * 30 + j) * cb + (CW); \
    ushort4 pk; pk.x = f2bf(fmaxf(AC[0]+(BS),0.f)); pk.y = f2bf(fmaxf(AC[1]+(BS),0.f)); \
    pk.z = f2bf(fmaxf(AC[2]+(BS),0.f)); pk.w = f2bf(fmaxf(AC[3]+(BS),0.f)); \
    *(ushort4*)(tp + rw) = pk; } }
  ST(a00, lc,      bs0, cw0)      ST(a01, 16 + lc, bs1, cw0)
  ST(a02, 32 + lc, bs2, cw0)      ST(a03, 48 + lc, bs3, cw0)
  ST(a04, 64 + lc, bs4, cw0)
  ST(a10, lc,      bs0, cw0 + 16) ST(a11, 16 + lc, bs1, cw0 + 16)
  ST(a12, 32 + lc, bs2, cw0 + 16) ST(a13, 48 + lc, bs3, cw0 + 16)
  ST(a14, 64 + lc, bs4, cw0 + 16)
#undef ST
}

// ---------- K6M: x2 via MFMA; wave = 2 o-tiles x 8 M-tiles, B in regs. grid (CB/128, 90) ----------
#define RD(D, TA, OFF) asm volatile("ds_read_b64_tr_b16 %0, %1 offset:" OFF : "=&v"(D) : "v"(TA));
#define TRS_EVEN(TA) \
  RD(p00,TA,"0")     RD(p01,TA,"1024")  RD(p10,TA,"8192")  RD(p11,TA,"9216") \
  RD(p20,TA,"16384") RD(p21,TA,"17408") RD(p30,TA,"24576") RD(p31,TA,"25600") \
  RD(p40,TA,"32768") RD(p41,TA,"33792") RD(p50,TA,"40960") RD(p51,TA,"41984") \
  RD(p60,TA,"49152") RD(p61,TA,"50176") RD(p70,TA,"57344") RD(p71,TA,"58368")
#define TRS_ODD(TA) \
  RD(p00,TA,"128")   RD(p01,TA,"1152")  RD(p10,TA,"8320")  RD(p11,TA,"9344") \
  RD(p20,TA,"16512") RD(p21,TA,"17536") RD(p30,TA,"24704") RD(p31,TA,"25728") \
  RD(p40,TA,"32896") RD(p41,TA,"33920") RD(p50,TA,"41088") RD(p51,TA,"42112") \
  RD(p60,TA,"49280") RD(p61,TA,"50304") RD(p70,TA,"57472") RD(p71,TA,"58496")

__global__ __launch_bounds__(256, 2) void k6m(Ctx C) {
  __shared__ u16 sA[32768];   // 64 KB
  const int tid = threadIdx.x;
  const int col0 = blockIdx.x * 128;
  const int gy = blockIdx.y;
  const int j = gy / 3, h3 = gy % 3;
  const size_t cb = (size_t)C.CB;
  const u16* __restrict__ A_ = C.A;
  const u16* __restrict__ WT2 = (const u16*)(C.F + OF_WT2);
  const float* __restrict__ F = C.F;

  const int x = tid & 63, wv = tid >> 6;
  const int klane = (x >> 1) & 3;
  const int m0s = ((x >> 3) << 4) + ((x & 1) << 3);
  const u16* zsrc = (const u16*)(F + OF_ZPAD);
#pragma unroll
  for (int p = 0; p < 16; ++p) {
    int k = p * 16 + wv * 4 + klane;
    const u16* src;
    bool pad = (k >= 150 && k < 160) || (k >= 235);
    if (pad) {
      src = zsrc;
    } else {
      int srow;
      if (k < 150) srow = R_TP + (h3 + (k & 1)) * 2250 + (k >> 1) * 30 + j;
      else { int kk = k - 160; int c = kk / 3; srow = R_VRP + (h3 + (kk - c * 3)) * 750 + c * 30 + j; }
      src = A_ + (size_t)srow * cb + col0 + m0s;
    }
    __builtin_amdgcn_global_load_lds(
        (const __attribute__((address_space(1))) void*)src,
        (__attribute__((address_space(3))) void*)&sA[(p * 4 + wv) * 512],
        16, 0, 0);
  }

  const int l = tid & 63, w = tid >> 6;
  const int lc = l & 15, q = l >> 4;
  const u16* wbA = WT2 + (size_t)(w * 32 + lc) * 256 + q * 8;
  const u16* wbB = WT2 + (size_t)(w * 32 + 16 + lc) * 256 + q * 8;
  bf16x8 b00 = *(const bf16x8*)(wbA + 0*32), b01 = *(const bf16x8*)(wbA + 1*32),
         b02 = *(const bf16x8*)(wbA + 2*32), b03 = *(const bf16x8*)(wbA + 3*32),
         b04 = *(const bf16x8*)(wbA + 4*32), b05 = *(const bf16x8*)(wbA + 5*32),
         b06 = *(const bf16x8*)(wbA + 6*32), b07 = *(const bf16x8*)(wbA + 7*32);
  bf16x8 b10 = *(const bf16x8*)(wbB + 0*32), b11 = *(const bf16x8*)(wbB + 1*32),
         b12 = *(const bf16x8*)(wbB + 2*32), b13 = *(const bf16x8*)(wbB + 3*32),
         b14 = *(const bf16x8*)(wbB + 4*32), b15 = *(const bf16x8*)(wbB + 5*32),
         b16 = *(const bf16x8*)(wbB + 6*32), b17 = *(const bf16x8*)(wbB + 7*32);

  float rbj = C.ra_b[j];
  u16* x2b = C.A + (size_t)R_X2 * cb;
  const size_t rowbase = (size_t)(h3 * 30 + j) * 125;
  const int o0 = w * 32 + lc;
  const int o1 = o0 + 16;
  const int o1c = (o1 < 125) ? o1 : 0;
  float bs0 = C.c2_b[o0] + C.ca_b[o0] + rbj * F[OF_CSAC + o0];
  float bs1 = C.c2_b[o1c] + C.ca_b[o1c] + rbj * F[OF_CSAC + o1c];

  __syncthreads();

  unsigned ldsbase = (unsigned)(size_t)(&sA[0]);
  const unsigned ta0 = ldsbase + (unsigned)((2 * q) * 1024 + lc * 8);
  const unsigned ta1 = ta0 + 256;
  const unsigned ta2 = ta0 + 512;
  const unsigned ta3 = ta0 + 768;

  u32x2 p00,p01, p10,p11, p20,p21, p30,p31, p40,p41, p50,p51, p60,p61, p70,p71;

  TRS_EVEN(ta0)

#define MM(FS, BA, BB) \
    a0 = __builtin_amdgcn_mfma_f32_16x16x32_bf16(FS, BA, a0, 0, 0, 0); \
    a1 = __builtin_amdgcn_mfma_f32_16x16x32_bf16(FS, BB, a1, 0, 0, 0);

#define MG_BODY(MG, ...) { \
    asm volatile("s_waitcnt lgkmcnt(0)" ::: "memory"); \
    __builtin_amdgcn_sched_barrier(0); \
    bf16x8 f0,f1,f2,f3,f4,f5,f6,f7; \
    { CvtAF c_; c_.p[0]=p00; c_.p[1]=p01; f0=c_.v; } \
    { CvtAF c_; c_.p[0]=p10; c_.p[1]=p11; f1=c_.v; } \
    { CvtAF c_; c_.p[0]=p20; c_.p[1]=p21; f2=c_.v; } \
    { CvtAF c_; c_.p[0]=p30; c_.p[1]=p31; f3=c_.v; } \
    { CvtAF c_; c_.p[0]=p40; c_.p[1]=p41; f4=c_.v; } \
    { CvtAF c_; c_.p[0]=p50; c_.p[1]=p51; f5=c_.v; } \
    { CvtAF c_; c_.p[0]=p60; c_.p[1]=p61; f6=c_.v; } \
    { CvtAF c_; c_.p[0]=p70; c_.p[1]=p71; f7=c_.v; } \
    __VA_ARGS__ \
    f32x4 a0 = {0.f,0.f,0.f,0.f}, a1 = {0.f,0.f,0.f,0.f}; \
    MM(f0,b00,b10) MM(f1,b01,b11) MM(f2,b02,b12) MM(f3,b03,b13) \
    MM(f4,b04,b14) MM(f5,b05,b15) MM(f6,b06,b16) MM(f7,b07,b17) \
    const int cw = col0 + (MG) * 16 + q * 4; \
    { ushort4 pk; pk.x = f2bf(a0[0]+bs0); pk.y = f2bf(a0[1]+bs0); \
      pk.z = f2bf(a0[2]+bs0); pk.w = f2bf(a0[3]+bs0); \
      *(ushort4*)(x2b + (rowbase + o0) * cb + cw) = pk; } \
    if (o1 < 125) { ushort4 pk; pk.x = f2bf(a1[0]+bs1); pk.y = f2bf(a1[1]+bs1); \
      pk.z = f2bf(a1[2]+bs1); pk.w = f2bf(a1[3]+bs1); \
      *(ushort4*)(x2b + (rowbase + o1) * cb + cw) = pk; } \
  }

  MG_BODY(0, TRS_ODD(ta0))
  MG_BODY(1, TRS_EVEN(ta1))
  MG_BODY(2, TRS_ODD(ta1))
  MG_BODY(3, TRS_EVEN(ta2))
  MG_BODY(4, TRS_ODD(ta2))
  MG_BODY(5, TRS_EVEN(ta3))
  MG_BODY(6, TRS_ODD(ta3))
  MG_BODY(7)
#undef MG_BODY
#undef MM
}

// ---------- K7: XJ_left + fold right into yAcc. grid (CB/256, 375) ----------
__global__ __launch_bounds__(256) void k7(Ctx C) {
  const int col = blockIdx.x * 256 + threadIdx.x;
  if (col >= C.CB) return;
  const int g = blockIdx.y;               // g = o*3 + h3
  const int o = g / 3, h3 = g % 3;
  const size_t cb = (size_t)C.CB;
  const u16* __restrict__ x2b = C.A + (size_t)R_X2 * cb;
  const float* __restrict__ SCT = C.F + OF_SCT;
  float4 A0=Z4,A1=Z4,A2=Z4,A3=Z4,A4=Z4;
  for (int j = 0; j < 30; ++j) {
    float xv = bf2f(x2b[(size_t)((h3 * 30 + j) * 125 + o) * cb + col]);
    const float4* __restrict__ W = (const float4*)(SCT + j * 20);
#define K7F(Aq, P) { float4 w = W[P]; Aq.x += w.x*xv; Aq.y += w.y*xv; Aq.z += w.z*xv; Aq.w += w.w*xv; }
    K7F(A0,0) K7F(A1,1) K7F(A2,2) K7F(A3,3) K7F(A4,4)
#undef K7F
  }
  u16* XJ = C.A + (size_t)R_XJ * cb;
  auto wq = [&](int qq, float v) { XJ[(size_t)(g * 10 + qq) * cb + col] = f2bf(v); };
  wq(0,A0.x); wq(1,A0.y); wq(2,A0.z); wq(3,A0.w);
  wq(4,A1.x); wq(5,A1.y); wq(6,A1.z); wq(7,A1.w);
  wq(8,A2.x); wq(9,A2.y);
  float s = C.fl_w[0]*A2.z + C.fl_w[1]*A2.w
          + C.fl_w[2]*A3.x + C.fl_w[3]*A3.y + C.fl_w[4]*A3.z + C.fl_w[5]*A3.w
          + C.fl_w[6]*A4.x + C.fl_w[7]*A4.y + C.fl_w[8]*A4.z + C.fl_w[9]*A4.w;
  atomicAdd(&C.yAcc[(size_t)h3 * C.CB + col], C.cc2_w[o] * s);
}

// ---------- K8a: 5 c per block, full o-contraction. grid (CB/256, 100) ----------
__global__ __launch_bounds__(256) void k8a(Ctx C) {
  const int col = blockIdx.x * 256 + threadIdx.x;
  if (col >= C.CB) return;
  const int g = blockIdx.y, cg = g / 20, rem = g % 20, hh = rem / 10, q = rem % 10;
  const size_t cb = (size_t)C.CB;
  const u16* __restrict__ XJ = C.A + (size_t)R_XJ * cb;
  const float* __restrict__ F = C.F;
  float4 A0 = Z4; float a4 = 0.f;
  const float* __restrict__ Wb = F + OF_CA2T + cg * 8;
  for (int k = 0; k < 250; ++k) {
    int o = k >> 1, dh = k & 1;
    float xv = bf2f(XJ[(size_t)((o * 3 + hh + dh) * 10 + q) * cb + col]);
    const float* __restrict__ wr = Wb + k * 40;
    float4 w0 = *(const float4*)wr;
    float w4 = wr[4];
    A0.x += w0.x * xv; A0.y += w0.y * xv; A0.z += w0.z * xv; A0.w += w0.w * xv;
    a4 += w4 * xv;
  }
  float s02 = F[OF_CS02 + q];
  float lb = C.l02_b[q];
  const int c0 = cg * 5;
  float part = 0.f;
  {
    float zc;
    zc = fmaxf(A0.x + C.ca2_b[c0+0] * s02 + lb, 0.f); part += C.cb2_w[(c0+0)*2+hh] * zc;
    zc = fmaxf(A0.y + C.ca2_b[c0+1] * s02 + lb, 0.f); part += C.cb2_w[(c0+1)*2+hh] * zc;
    zc = fmaxf(A0.z + C.ca2_b[c0+2] * s02 + lb, 0.f); part += C.cb2_w[(c0+2)*2+hh] * zc;
    zc = fmaxf(A0.w + C.ca2_b[c0+3] * s02 + lb, 0.f); part += C.cb2_w[(c0+3)*2+hh] * zc;
    zc = fmaxf(a4   + C.ca2_b[c0+4] * s02 + lb, 0.f); part += C.cb2_w[(c0+4)*2+hh] * zc;
  }
  atomicAdd(&C.zAcc[col], C.fl_w[q] * part);
}

// ---------- K8c: out = const + zAcc + yAcc[h]. grid (CB/256, 1) ----------
__global__ __launch_bounds__(256) void k8c(Ctx C) {
  const int col = blockIdx.x * 256 + threadIdx.x;
  if (col >= C.CB) return;
  float scc2 = C.F[OF_CSCC2];
  float cst = C.fl_b[0];
#pragma unroll
  for (int q = 0; q < 10; ++q)
    cst += C.fl_w[q] * (C.cb2_b[0] + C.r02_b[q] * scc2 + C.cc2_b[0]);
  float za = C.zAcc[col];
#pragma unroll
  for (int h = 0; h < 3; ++h)
    C.out[(size_t)(C.b0g + col) * 3 + h] = cst + za + C.yAcc[(size_t)h * C.CB + col];
}

extern "C" void kernel_launch(void* const* d_in, const int* in_sizes, int n_in,
                              void* d_out, int out_size, void* d_ws, size_t ws_size,
                              hipStream_t stream) {
  (void)n_in; (void)out_size;
  Ctx C;
  C.x     = (const float*)d_in[0];
  C.ca1_w = (const float*)d_in[1];  C.ca1_b = (const float*)d_in[2];
  C.l01_w = (const float*)d_in[3];  C.l01_b = (const float*)d_in[4];
  C.cb1_w = (const float*)d_in[5];  C.cb1_b = (const float*)d_in[6];
  C.cc1_w = (const float*)d_in[7];  C.cc1_b = (const float*)d_in[8];
  C.r01_w = (const float*)d_in[9];  C.r01_b = (const float*)d_in[10];
  C.c1_w  = (const float*)d_in[11]; C.c1_b  = (const float*)d_in[12];
  C.l1_w  = (const float*)d_in[13]; C.l1_b  = (const float*)d_in[14];
  C.c2_w  = (const float*)d_in[15]; C.c2_b  = (const float*)d_in[16];
  C.ca_w  = (const float*)d_in[17]; C.ca_b  = (const float*)d_in[18];
  C.ra_w  = (const float*)d_in[19]; C.ra_b  = (const float*)d_in[20];
  C.ca2_w = (const float*)d_in[21]; C.ca2_b = (const float*)d_in[22];
  C.l02_w = (const float*)d_in[23]; C.l02_b = (const float*)d_in[24];
  C.cb2_w = (const float*)d_in[25]; C.cb2_b = (const float*)d_in[26];
  C.cc2_w = (const float*)d_in[27]; C.cc2_b = (const float*)d_in[28];
  C.r02_w = (const float*)d_in[29]; C.r02_b = (const float*)d_in[30];
  C.fl_w  = (const float*)d_in[31]; C.fl_b  = (const float*)d_in[32];
  C.out   = (float*)d_out;

  const int B = in_sizes[0] / 635;

  int CB = 4096;
  if (CB > B) CB = B;
  size_t accoff, actoff;
  for (;;) {
    accoff = ((size_t)F32_TOTAL * 4 + 255) & ~(size_t)255;
    actoff = (accoff + (size_t)4 * CB * 4 + 255) & ~(size_t)255;
    if (CB <= 256 || actoff + (size_t)ROWS_TOTAL * CB * 2 <= ws_size) break;
    CB >>= 1;
  }
  C.F = (float*)d_ws;
  C.zAcc = (float*)((char*)d_ws + accoff);
  C.yAcc = C.zAcc + CB;
  C.A = (u16*)((char*)d_ws + actoff);
  C.CB = CB;

  C.b0g = 0;
  k0c<<<dim3(32), dim3(256), 0, stream>>>(C);

  const int bt64 = CB / 64, bt128 = CB / 128, bt256 = (CB + 255) / 256;
  for (int b0 = 0; b0 < B; b0 += CB) {
    C.b0g = b0;
    hipMemsetAsync(C.zAcc, 0, (size_t)4 * CB * sizeof(float), stream);
    k0t<<<dim3(bt64, 10),   dim3(256), 0, stream>>>(C);
    k1 <<<dim3(bt256, 30),  dim3(256), 0, stream>>>(C);
    k2 <<<dim3(bt256, 75),  dim3(256), 0, stream>>>(C);
    k3 <<<dim3(bt256, 60),  dim3(256), 0, stream>>>(C);
    k4 <<<dim3(bt256, 300), dim3(256), 0, stream>>>(C);
    k5m<<<dim3(bt128, 120), dim3(256), 0, stream>>>(C);
    k6m<<<dim3(bt128, 90),  dim3(256), 0, stream>>>(C);
    k7 <<<dim3(bt256, 375), dim3(256), 0, stream>>>(C);
    k8a<<<dim3(bt256, 100), dim3(256), 0, stream>>>(C);
    k8c<<<dim3(bt256, 1),   dim3(256), 0, stream>>>(C);
  }
}